// Round 1
// baseline (1563.714 us; speedup 1.0000x reference)
//
#include <hip/hip_runtime.h>
#include <hip/hip_bf16.h>
#include <math.h>

#define NSEQ 2048
#define NPOS 4095   // 2*NSEQ-1
#define NH   8
#define NBAT 2

__device__ __forceinline__ float bf2f(unsigned int u) {
  return __uint_as_float(u << 16);
}
__device__ __forceinline__ void unpack8(float* dst, uint4 v) {
  dst[0] = bf2f(v.x & 0xffffu); dst[1] = bf2f(v.x >> 16);
  dst[2] = bf2f(v.y & 0xffffu); dst[3] = bf2f(v.y >> 16);
  dst[4] = bf2f(v.z & 0xffffu); dst[5] = bf2f(v.z >> 16);
  dst[6] = bf2f(v.w & 0xffffu); dst[7] = bf2f(v.w >> 16);
}

// ---------------- positional embedding pos[NPOS][192] ----------------
__global__ __launch_bounds__(64) void pos_embed_k(float* __restrict__ pos) {
  int t = blockIdx.x * 64 + threadIdx.x;
  if (t >= NPOS) return;
  float dist = (float)(t - (NSEQ - 1));
  float ad = fabsf(dist);
  float sgn = (dist > 0.f) ? 1.f : ((dist < 0.f) ? -1.f : 0.f);
  double add = (double)ad;
  float gm[32]; float gmax = 0.f;
  #pragma unroll
  for (int f = 0; f < 32; f++) {
    // mean = linspace(64, 2048, 32) = 64*(f+1) exactly; stddev = 32
    double mean = 64.0 * (double)(f + 1);
    double conc = (mean / 32.0) * (mean / 32.0);
    double rate = mean / 1024.0;
    double p = 0.0;
    if (ad > 0.f) {
      double lu = (conc - 1.0) * log(add) - rate * add;    // xlogy(conc-1, ad) - rate*ad
      double ln = lgamma(conc) - conc * log(rate);
      p = exp(lu - ln);
    }
    float pf = (float)p + 1e-8f;
    gm[f] = pf; gmax = fmaxf(gmax, pf);
  }
  float inv = 1.f / gmax;
  float* row = pos + (size_t)t * 192;
  #pragma unroll
  for (int f = 0; f < 32; f++) {
    float hl = exp2f(3.f + 8.f * (float)f * (1.f / 31.f));  // 2^linspace(3,11,32)
    float fe = exp2f(-ad / hl);                             // exp(-ln2/hl * ad)
    float cw = exp2f((float)(f + 1)) - 1.f;
    float fc = (cw > ad) ? 1.f : 0.f;
    float fg = gm[f] * inv;
    row[f]       = fe;       row[32 + f]  = fc;       row[64 + f]  = fg;
    row[96 + f]  = sgn * fe; row[128 + f] = sgn * fc; row[160 + f] = sgn * fg;
  }
}

// ---------------- generic tiled SGEMM, 64x64 tile, BK=16 ----------------
// MODE 0: head-split  out[(b*NH+h)*NSEQ*64 + row*64 + d]            (q, v1, v2)
// MODE 1: head-split, val = val*0.125 + extra[col]                  (kb = k*scale + rpb)
// MODE 2: relq        out[(h*NPOS + m)*64 + d]
// MODE 3: plain       out[m*Nout + col] = val + extra[col]          (output proj)
template<int MODE>
__global__ __launch_bounds__(256) void sgemm_k(
    const float* __restrict__ A, const float* __restrict__ W,
    float* __restrict__ out, const float* __restrict__ extra,
    int M, int K, int Nout)
{
  __shared__ float As[16][65];  // As[k][m]
  __shared__ float Ws[16][65];  // Ws[k][n]
  int tid = threadIdx.x;
  int m0 = blockIdx.y * 64, n0 = blockIdx.x * 64;
  int tm = tid >> 4, tn = tid & 15;
  int am = tid >> 2, ak = (tid & 3) * 4;
  int wk = tid >> 4, wn = (tid & 15) * 4;
  float acc[4][4] = {};
  for (int k0 = 0; k0 < K; k0 += 16) {
    float4 av = make_float4(0.f, 0.f, 0.f, 0.f);
    if (m0 + am < M) av = *(const float4*)&A[(size_t)(m0 + am) * K + k0 + ak];
    As[ak + 0][am] = av.x; As[ak + 1][am] = av.y;
    As[ak + 2][am] = av.z; As[ak + 3][am] = av.w;
    float4 wv = *(const float4*)&W[(size_t)(k0 + wk) * Nout + n0 + wn];
    Ws[wk][wn + 0] = wv.x; Ws[wk][wn + 1] = wv.y;
    Ws[wk][wn + 2] = wv.z; Ws[wk][wn + 3] = wv.w;
    __syncthreads();
    #pragma unroll
    for (int kk = 0; kk < 16; kk++) {
      float a[4], b[4];
      #pragma unroll
      for (int r = 0; r < 4; r++) a[r] = As[kk][tm * 4 + r];
      #pragma unroll
      for (int c = 0; c < 4; c++) b[c] = Ws[kk][tn * 4 + c];
      #pragma unroll
      for (int r = 0; r < 4; r++)
        #pragma unroll
        for (int c = 0; c < 4; c++) acc[r][c] += a[r] * b[c];
    }
    __syncthreads();
  }
  #pragma unroll
  for (int r = 0; r < 4; r++) {
    int m = m0 + tm * 4 + r;
    if (m >= M) continue;
    float4 o = make_float4(acc[r][0], acc[r][1], acc[r][2], acc[r][3]);
    if constexpr (MODE == 0 || MODE == 1) {
      if constexpr (MODE == 1) {
        o.x = o.x * 0.125f + extra[n0 + tn * 4 + 0];
        o.y = o.y * 0.125f + extra[n0 + tn * 4 + 1];
        o.z = o.z * 0.125f + extra[n0 + tn * 4 + 2];
        o.w = o.w * 0.125f + extra[n0 + tn * 4 + 3];
      }
      int b = m >> 11, row = m & (NSEQ - 1), h = n0 >> 6;
      *(float4*)&out[(((size_t)(b * NH + h)) * NSEQ + row) * 64 + tn * 4] = o;
    } else if constexpr (MODE == 2) {
      int h = n0 >> 6;
      *(float4*)&out[((size_t)h * NPOS + m) * 64 + tn * 4] = o;
    } else {
      o.x += extra[n0 + tn * 4 + 0]; o.y += extra[n0 + tn * 4 + 1];
      o.z += extra[n0 + tn * 4 + 2]; o.w += extra[n0 + tn * 4 + 3];
      *(float4*)&out[(size_t)m * Nout + n0 + tn * 4] = o;
    }
  }
}

// ---------------- fused logits: logits'[i,j] = sum_d kb[j,d]*(q[i,d] + r[N-1+i-j, d]) ----
// (exactly logits_ref minus a per-row constant q_i . rpb -> softmax-invariant)
__global__ __launch_bounds__(256) void logits_k(
    const float* __restrict__ q, const float* __restrict__ kb,
    const float* __restrict__ relq, float* __restrict__ logits, int bh0)
{
  __shared__ float Qs[64][65];
  __shared__ float KBs[64][65];
  __shared__ float Rs[127][65];
  int z = blockIdx.z;
  int bh = bh0 + z;
  int h = bh & 7;
  int i0 = blockIdx.y * 64, j0 = blockIdx.x * 64;
  int tid = threadIdx.x;
  {
    int li = tid >> 2, dq = (tid & 3) * 16;
    const float* qp = q  + ((size_t)bh * NSEQ + i0 + li) * 64 + dq;
    const float* kp = kb + ((size_t)bh * NSEQ + j0 + li) * 64 + dq;
    #pragma unroll
    for (int u = 0; u < 4; u++) {
      float4 a = *(const float4*)(qp + u * 4);
      Qs[li][dq + u * 4 + 0] = a.x; Qs[li][dq + u * 4 + 1] = a.y;
      Qs[li][dq + u * 4 + 2] = a.z; Qs[li][dq + u * 4 + 3] = a.w;
      float4 b = *(const float4*)(kp + u * 4);
      KBs[li][dq + u * 4 + 0] = b.x; KBs[li][dq + u * 4 + 1] = b.y;
      KBs[li][dq + u * 4 + 2] = b.z; KBs[li][dq + u * 4 + 3] = b.w;
    }
    int rr = tid >> 1, rd = (tid & 1) * 32;
    if (rr < 127) {
      int mbase = (NSEQ - 1) + i0 - j0 - 63;   // always in [0, NPOS-127] since n1==n2
      const float* rp = relq + ((size_t)h * NPOS + mbase + rr) * 64 + rd;
      #pragma unroll
      for (int u = 0; u < 8; u++) {
        float4 a = *(const float4*)(rp + u * 4);
        Rs[rr][rd + u * 4 + 0] = a.x; Rs[rr][rd + u * 4 + 1] = a.y;
        Rs[rr][rd + u * 4 + 2] = a.z; Rs[rr][rd + u * 4 + 3] = a.w;
      }
    }
  }
  __syncthreads();
  int tm = tid >> 4, tn = tid & 15;
  float acc[4][4] = {};
  int s0 = 4 * (tm - tn) + 60;   // s for (r,c) is s0 + (r-c+3), in [0,126]
  #pragma unroll 4
  for (int d = 0; d < 64; d++) {
    float qv[4], kv[4], rv[7];
    #pragma unroll
    for (int r = 0; r < 4; r++) qv[r] = Qs[tm * 4 + r][d];
    #pragma unroll
    for (int c = 0; c < 4; c++) kv[c] = KBs[tn * 4 + c][d];
    #pragma unroll
    for (int u = 0; u < 7; u++) rv[u] = Rs[s0 + u][d];
    #pragma unroll
    for (int r = 0; r < 4; r++)
      #pragma unroll
      for (int c = 0; c < 4; c++)
        acc[r][c] += kv[c] * (qv[r] + rv[r - c + 3]);
  }
  float* op = logits + ((size_t)z * NSEQ + i0 + tm * 4) * NSEQ + j0 + tn * 4;
  #pragma unroll
  for (int r = 0; r < 4; r++)
    *(float4*)(op + (size_t)r * NSEQ) =
        make_float4(acc[r][0], acc[r][1], acc[r][2], acc[r][3]);
}

// ---------------- row softmax f32 -> bf16 ----------------
__global__ __launch_bounds__(256) void softmax_k(const float* __restrict__ logits,
                                                 __hip_bfloat16* __restrict__ attn) {
  size_t row = blockIdx.x;
  const float* lp = logits + row * NSEQ;
  int tid = threadIdx.x;
  float v[8]; float mx = -3.4e38f;
  #pragma unroll
  for (int u = 0; u < 8; u++) { v[u] = lp[tid + u * 256]; mx = fmaxf(mx, v[u]); }
  #pragma unroll
  for (int off = 32; off >= 1; off >>= 1) mx = fmaxf(mx, __shfl_down(mx, off));
  __shared__ float redm[4], reds[4];
  if ((tid & 63) == 0) redm[tid >> 6] = mx;
  __syncthreads();
  mx = fmaxf(fmaxf(redm[0], redm[1]), fmaxf(redm[2], redm[3]));
  float s = 0.f;
  #pragma unroll
  for (int u = 0; u < 8; u++) { v[u] = expf(v[u] - mx); s += v[u]; }
  #pragma unroll
  for (int off = 32; off >= 1; off >>= 1) s += __shfl_down(s, off);
  if ((tid & 63) == 0) reds[tid >> 6] = s;
  __syncthreads();
  s = reds[0] + reds[1] + reds[2] + reds[3];
  float inv = 1.f / s;
  __hip_bfloat16* ap = attn + row * NSEQ;
  #pragma unroll
  for (int u = 0; u < 8; u++) ap[tid + u * 256] = __float2bfloat16(v[u] * inv);
}

// ---------------- out1: o1acc[b][i][h*64+d] = sum_j attn[i,j] * v2[j,d] ----------------
__global__ __launch_bounds__(256) void pv1_k(const __hip_bfloat16* __restrict__ attn,
    const float* __restrict__ v2, float* __restrict__ o1acc, int bh0)
{
  __shared__ float As[64][33];   // [i][k]
  __shared__ float Vs[32][65];   // [k][d]
  int z = blockIdx.y; int bh = bh0 + z; int b = bh >> 3, h = bh & 7;
  int i0 = blockIdx.x * 64;
  int tid = threadIdx.x;
  int tm = tid >> 4, tn = tid & 15;
  int li = tid >> 2, kq = (tid & 3) * 8;
  int kv = tid >> 3, dv = (tid & 7) * 8;
  const unsigned short* ab = (const unsigned short*)attn;
  float acc[4][4] = {};
  for (int k0 = 0; k0 < NSEQ; k0 += 32) {
    uint4 av = *(const uint4*)&ab[((size_t)z * NSEQ + i0 + li) * NSEQ + k0 + kq];
    unpack8(&As[li][kq], av);
    float4 w0 = *(const float4*)&v2[((size_t)bh * NSEQ + k0 + kv) * 64 + dv];
    float4 w1 = *(const float4*)&v2[((size_t)bh * NSEQ + k0 + kv) * 64 + dv + 4];
    Vs[kv][dv + 0] = w0.x; Vs[kv][dv + 1] = w0.y; Vs[kv][dv + 2] = w0.z; Vs[kv][dv + 3] = w0.w;
    Vs[kv][dv + 4] = w1.x; Vs[kv][dv + 5] = w1.y; Vs[kv][dv + 6] = w1.z; Vs[kv][dv + 7] = w1.w;
    __syncthreads();
    #pragma unroll 8
    for (int kk = 0; kk < 32; kk++) {
      float a[4], w[4];
      #pragma unroll
      for (int r = 0; r < 4; r++) a[r] = As[tm * 4 + r][kk];
      #pragma unroll
      for (int c = 0; c < 4; c++) w[c] = Vs[kk][tn * 4 + c];
      #pragma unroll
      for (int r = 0; r < 4; r++)
        #pragma unroll
        for (int c = 0; c < 4; c++) acc[r][c] += a[r] * w[c];
    }
    __syncthreads();
  }
  #pragma unroll
  for (int r = 0; r < 4; r++) {
    float4 o = make_float4(acc[r][0], acc[r][1], acc[r][2], acc[r][3]);
    *(float4*)&o1acc[((size_t)b * NSEQ + i0 + tm * 4 + r) * 512 + h * 64 + tn * 4] = o;
  }
}

// ---------------- out2: o2acc[b][j'][h*64+d] = sum_i attn[i,j'] * v1[i,d] ----------------
__global__ __launch_bounds__(256) void pv2_k(const __hip_bfloat16* __restrict__ attn,
    const float* __restrict__ v1, float* __restrict__ o2acc, int bh0)
{
  __shared__ float As[32][65];   // [k][j']
  __shared__ float Vs[32][65];   // [k][d]
  int z = blockIdx.y; int bh = bh0 + z; int b = bh >> 3, h = bh & 7;
  int j0 = blockIdx.x * 64;
  int tid = threadIdx.x;
  int tm = tid >> 4, tn = tid & 15;
  int kka = tid >> 3, jq = (tid & 7) * 8;
  int kv = tid >> 3, dv = (tid & 7) * 8;
  const unsigned short* ab = (const unsigned short*)attn;
  float acc[4][4] = {};
  for (int k0 = 0; k0 < NSEQ; k0 += 32) {
    uint4 av = *(const uint4*)&ab[((size_t)z * NSEQ + k0 + kka) * NSEQ + j0 + jq];
    unpack8(&As[kka][jq], av);
    float4 w0 = *(const float4*)&v1[((size_t)bh * NSEQ + k0 + kv) * 64 + dv];
    float4 w1 = *(const float4*)&v1[((size_t)bh * NSEQ + k0 + kv) * 64 + dv + 4];
    Vs[kv][dv + 0] = w0.x; Vs[kv][dv + 1] = w0.y; Vs[kv][dv + 2] = w0.z; Vs[kv][dv + 3] = w0.w;
    Vs[kv][dv + 4] = w1.x; Vs[kv][dv + 5] = w1.y; Vs[kv][dv + 6] = w1.z; Vs[kv][dv + 7] = w1.w;
    __syncthreads();
    #pragma unroll 8
    for (int kk = 0; kk < 32; kk++) {
      float a[4], w[4];
      #pragma unroll
      for (int r = 0; r < 4; r++) a[r] = As[kk][tm * 4 + r];
      #pragma unroll
      for (int c = 0; c < 4; c++) w[c] = Vs[kk][tn * 4 + c];
      #pragma unroll
      for (int r = 0; r < 4; r++)
        #pragma unroll
        for (int c = 0; c < 4; c++) acc[r][c] += a[r] * w[c];
    }
    __syncthreads();
  }
  #pragma unroll
  for (int r = 0; r < 4; r++) {
    float4 o = make_float4(acc[r][0], acc[r][1], acc[r][2], acc[r][3]);
    *(float4*)&o2acc[((size_t)b * NSEQ + j0 + tm * 4 + r) * 512 + h * 64 + tn * 4] = o;
  }
}

extern "C" void kernel_launch(void* const* d_in, const int* in_sizes, int n_in,
                              void* d_out, int out_size, void* d_ws, size_t ws_size,
                              hipStream_t stream) {
  const float* x1   = (const float*)d_in[0];   // [2,2048,1024]
  const float* x2   = (const float*)d_in[1];   // [2,2048,512]
  const float* Wq   = (const float*)d_in[2];   // [1024,512]
  const float* Wk   = (const float*)d_in[3];   // [512,512]
  const float* Wv1  = (const float*)d_in[4];   // [1024,512]
  const float* Wv2  = (const float*)d_in[5];   // [512,512]
  const float* Wrel = (const float*)d_in[6];   // [192,512]
  const float* rpb  = (const float*)d_in[7];   // [1,8,1,64] -> flat [512]
  const float* Wo1  = (const float*)d_in[8];   // [512,1024]
  const float* bo1  = (const float*)d_in[9];   // [1024]
  const float* Wo2  = (const float*)d_in[10];  // [512,1024]
  const float* bo2  = (const float*)d_in[11];  // [1024]
  float* out = (float*)d_out;

  float* ws = (float*)d_ws;
  size_t off = 0;
  float* pos   = ws + off; off += (size_t)NPOS * 192;        // 786,240
  float* relq  = ws + off; off += (size_t)NH * NPOS * 64;    // 2,096,640
  float* q     = ws + off; off += (size_t)16 * NSEQ * 64;    // 2,097,152 each
  float* kb    = ws + off; off += (size_t)16 * NSEQ * 64;
  float* v1    = ws + off; off += (size_t)16 * NSEQ * 64;
  float* v2    = ws + off; off += (size_t)16 * NSEQ * 64;
  float* o1acc = ws + off; off += (size_t)NBAT * NSEQ * 512;
  float* o2acc = ws + off; off += (size_t)NBAT * NSEQ * 512;
  size_t baseF = off;

  // largest bh-chunk whose logits(f32)+attn(bf16) buffers fit the workspace
  int chunk = 1;
  for (int c = 8; c >= 1; c >>= 1) {
    size_t needB = (baseF + (size_t)c * NSEQ * NSEQ + (size_t)c * NSEQ * NSEQ / 2) * 4;
    if (needB <= ws_size) { chunk = c; break; }
  }
  float* logits = ws + baseF;
  __hip_bfloat16* attn = (__hip_bfloat16*)(logits + (size_t)chunk * NSEQ * NSEQ);

  pos_embed_k<<<(NPOS + 63) / 64, 64, 0, stream>>>(pos);
  sgemm_k<2><<<dim3(8, 64), 256, 0, stream>>>(pos, Wrel, relq, nullptr, NPOS, 192, 512);
  sgemm_k<0><<<dim3(8, 64), 256, 0, stream>>>(x1, Wq, q, nullptr, NBAT * NSEQ, 1024, 512);
  sgemm_k<1><<<dim3(8, 64), 256, 0, stream>>>(x2, Wk, kb, rpb, NBAT * NSEQ, 512, 512);
  sgemm_k<0><<<dim3(8, 64), 256, 0, stream>>>(x1, Wv1, v1, nullptr, NBAT * NSEQ, 1024, 512);
  sgemm_k<0><<<dim3(8, 64), 256, 0, stream>>>(x2, Wv2, v2, nullptr, NBAT * NSEQ, 512, 512);

  for (int bh0 = 0; bh0 < 16; bh0 += chunk) {
    logits_k<<<dim3(32, 32, chunk), 256, 0, stream>>>(q, kb, relq, logits, bh0);
    softmax_k<<<chunk * NSEQ, 256, 0, stream>>>(logits, attn);
    pv1_k<<<dim3(32, chunk), 256, 0, stream>>>(attn, v2, o1acc, bh0);
    pv2_k<<<dim3(32, chunk), 256, 0, stream>>>(attn, v1, o2acc, bh0);
  }

  sgemm_k<3><<<dim3(16, 64), 256, 0, stream>>>(o1acc, Wo1, out, bo1, NBAT * NSEQ, 512, 1024);
  sgemm_k<3><<<dim3(16, 64), 256, 0, stream>>>(o2acc, Wo2, out + (size_t)NBAT * NSEQ * 1024,
                                               bo2, NBAT * NSEQ, 512, 1024);
}

// Round 2
// 753.497 us; speedup vs baseline: 2.0753x; 2.0753x over previous
//
#include <hip/hip_runtime.h>
#include <math.h>

#define NSEQ 2048
#define NPOS 4095   // 2*NSEQ-1
#define NH   8
#define NBAT 2

typedef _Float16 f16;
typedef f16 f16x8 __attribute__((ext_vector_type(8)));
typedef float f32x4 __attribute__((ext_vector_type(4)));

#define MFMA16(a, b, c) __builtin_amdgcn_mfma_f32_16x16x32_f16(a, b, c, 0, 0, 0)

__device__ __forceinline__ f16x8 cvt8(float4 a, float4 b) {
  f16x8 r = {(f16)a.x, (f16)a.y, (f16)a.z, (f16)a.w,
             (f16)b.x, (f16)b.y, (f16)b.z, (f16)b.w};
  return r;
}

// ---------------- positional embedding pos[NPOS][192] (f32) ----------------
__global__ __launch_bounds__(64) void pos_embed_k(float* __restrict__ pos) {
  int t = blockIdx.x * 64 + threadIdx.x;
  if (t >= NPOS) return;
  float dist = (float)(t - (NSEQ - 1));
  float ad = fabsf(dist);
  float sgn = (dist > 0.f) ? 1.f : ((dist < 0.f) ? -1.f : 0.f);
  double add = (double)ad;
  float gm[32]; float gmax = 0.f;
  #pragma unroll
  for (int f = 0; f < 32; f++) {
    double mean = 64.0 * (double)(f + 1);     // linspace(64,2048,32)
    double conc = (mean / 32.0) * (mean / 32.0);
    double rate = mean / 1024.0;
    double p = 0.0;
    if (ad > 0.f) {
      double lu = (conc - 1.0) * log(add) - rate * add;
      double ln = lgamma(conc) - conc * log(rate);
      p = exp(lu - ln);
    }
    float pf = (float)p + 1e-8f;
    gm[f] = pf; gmax = fmaxf(gmax, pf);
  }
  float inv = 1.f / gmax;
  float* row = pos + (size_t)t * 192;
  #pragma unroll
  for (int f = 0; f < 32; f++) {
    float hl = exp2f(3.f + 8.f * (float)f * (1.f / 31.f));
    float fe = exp2f(-ad / hl);
    float cw = exp2f((float)(f + 1)) - 1.f;
    float fc = (cw > ad) ? 1.f : 0.f;
    float fg = gm[f] * inv;
    row[f]       = fe;       row[32 + f]  = fc;       row[64 + f]  = fg;
    row[96 + f]  = sgn * fe; row[128 + f] = sgn * fc; row[160 + f] = sgn * fg;
  }
}

// ---------------- MFMA f16 GEMM: C[M,N] = A[M,K] * W[K,N], f32 in/out ------
// MODE 0: head-split out[(b*NH+h)*NSEQ*64 + row*64 + d]
// MODE 1: head-split, val = val*0.125 + extra[n]          (kb)
// MODE 2: relq out[(h*NPOS + m)*64 + d]
// MODE 3: plain out[m*Nout+n] = val + extra[n]            (out proj)
template<int MODE>
__global__ __launch_bounds__(256) void mgemm_k(
    const float* __restrict__ A, const float* __restrict__ W,
    float* __restrict__ out, const float* __restrict__ extra,
    int M, int K, int Nout)
{
  __shared__ f16 As[64][40];   // [m][k]
  __shared__ f16 Bs[64][40];   // [n][k]  (transposed)
  int tid = threadIdx.x;
  int w = tid >> 6, lane = tid & 63;
  int m0 = blockIdx.y * 64, n0 = blockIdx.x * 64;
  int ar = tid >> 2, ac = (tid & 3) * 8;
  int bk = tid >> 3, bn = (tid & 7) * 8;
  f32x4 acc[4] = {};
  for (int k0 = 0; k0 < K; k0 += 32) {
    float4 a0 = make_float4(0.f,0.f,0.f,0.f), a1 = a0;
    if (m0 + ar < M) {
      const float* ap = &A[(size_t)(m0 + ar) * K + k0 + ac];
      a0 = *(const float4*)ap; a1 = *(const float4*)(ap + 4);
    }
    *(f16x8*)&As[ar][ac] = cvt8(a0, a1);
    const float* bp = &W[(size_t)(k0 + bk) * Nout + n0 + bn];
    float4 b0 = *(const float4*)bp, b1 = *(const float4*)(bp + 4);
    Bs[bn+0][bk] = (f16)b0.x; Bs[bn+1][bk] = (f16)b0.y;
    Bs[bn+2][bk] = (f16)b0.z; Bs[bn+3][bk] = (f16)b0.w;
    Bs[bn+4][bk] = (f16)b1.x; Bs[bn+5][bk] = (f16)b1.y;
    Bs[bn+6][bk] = (f16)b1.z; Bs[bn+7][bk] = (f16)b1.w;
    __syncthreads();
    f16x8 af = *(const f16x8*)&As[16*w + (lane & 15)][8*(lane >> 4)];
    #pragma unroll
    for (int nt = 0; nt < 4; nt++) {
      f16x8 bf = *(const f16x8*)&Bs[16*nt + (lane & 15)][8*(lane >> 4)];
      acc[nt] = MFMA16(af, bf, acc[nt]);
    }
    __syncthreads();
  }
  #pragma unroll
  for (int nt = 0; nt < 4; nt++) {
    #pragma unroll
    for (int r = 0; r < 4; r++) {
      int m = m0 + 16*w + 4*(lane >> 4) + r;
      int n = n0 + 16*nt + (lane & 15);
      if (m >= M) continue;
      float v = acc[nt][r];
      if constexpr (MODE == 0 || MODE == 1) {
        if constexpr (MODE == 1) v = v * 0.125f + extra[n];
        int b = m >> 11, row = m & (NSEQ - 1), h = n >> 6, d = n & 63;
        out[(((size_t)(b * NH + h)) * NSEQ + row) * 64 + d] = v;
      } else if constexpr (MODE == 2) {
        int h = n >> 6, d = n & 63;
        out[((size_t)h * NPOS + m) * 64 + d] = v;
      } else {
        out[(size_t)m * Nout + n] = v + extra[n];
      }
    }
  }
}

// ---------------- fused logits (MFMA f16) ----------------
// logits'[i,j] = sum_d q[i,d]*kb[j,d]  +  G[j, i-j+63]
// G[j,n] = sum_d kb[j,d]*relq[nbase+n,d],  nbase = NSEQ-1+i0-j0-63
__global__ __launch_bounds__(256) void logits_k(
    const float* __restrict__ q, const float* __restrict__ kb,
    const float* __restrict__ relq, float* __restrict__ logits, int bh0)
{
  __shared__ char smem[36864 + 768];
  f16 (*Qs)[72]  = (f16(*)[72])smem;             //  9216 B
  f16 (*KBs)[72] = (f16(*)[72])(smem + 9216);    //  9216 B
  f16 (*Rs)[72]  = (f16(*)[72])(smem + 18432);   // 18432 B
  float (*G)[132] = (float(*)[132])smem;         // overlay: 33792 B

  int z = blockIdx.z;
  int bh = bh0 + z;
  int h = bh & 7;
  int i0 = blockIdx.y * 64, j0 = blockIdx.x * 64;
  int tid = threadIdx.x;
  int w = tid >> 6, lane = tid & 63;
  int wa = w >> 1, wb = w & 1;
  {
    int row = tid >> 2, c0 = (tid & 3) * 16;
    const float* qp = q  + ((size_t)bh * NSEQ + i0 + row) * 64 + c0;
    const float* kp = kb + ((size_t)bh * NSEQ + j0 + row) * 64 + c0;
    *(f16x8*)&Qs[row][c0]      = cvt8(*(const float4*)qp, *(const float4*)(qp+4));
    *(f16x8*)&Qs[row][c0+8]    = cvt8(*(const float4*)(qp+8), *(const float4*)(qp+12));
    *(f16x8*)&KBs[row][c0]     = cvt8(*(const float4*)kp, *(const float4*)(kp+4));
    *(f16x8*)&KBs[row][c0+8]   = cvt8(*(const float4*)(kp+8), *(const float4*)(kp+12));
    int rr = tid >> 1, rd = (tid & 1) * 32;
    int nbase = (NSEQ - 1) + i0 - j0 - 63;   // in [0, NPOS-127]
    const float* rp = relq + ((size_t)h * NPOS + nbase + rr) * 64 + rd;
    #pragma unroll
    for (int u = 0; u < 4; u++)
      *(f16x8*)&Rs[rr][rd + u*8] =
          cvt8(*(const float4*)(rp + u*8), *(const float4*)(rp + u*8 + 4));
  }
  __syncthreads();

  f32x4 cacc[2][2] = {};   // content: i-strips {2wa,2wa+1}, j-strips {2wb,2wb+1}
  f32x4 gacc[2][4] = {};   // G: j-strips {2wa,2wa+1}, n-strips {4wb..4wb+3}
  #pragma unroll
  for (int kh = 0; kh < 2; kh++) {
    int kof = 32*kh + 8*(lane >> 4);
    f16x8 qa[2], ka[2], kbf[2];
    #pragma unroll
    for (int x = 0; x < 2; x++) {
      qa[x]  = *(const f16x8*)&Qs[16*(2*wa+x) + (lane & 15)][kof];
      ka[x]  = *(const f16x8*)&KBs[16*(2*wa+x) + (lane & 15)][kof];
      kbf[x] = *(const f16x8*)&KBs[16*(2*wb+x) + (lane & 15)][kof];
    }
    #pragma unroll
    for (int x = 0; x < 2; x++)
      #pragma unroll
      for (int y = 0; y < 2; y++)
        cacc[x][y] = MFMA16(qa[x], kbf[y], cacc[x][y]);
    #pragma unroll
    for (int y = 0; y < 4; y++) {
      f16x8 rb = *(const f16x8*)&Rs[16*(4*wb+y) + (lane & 15)][kof];
      #pragma unroll
      for (int x = 0; x < 2; x++)
        gacc[x][y] = MFMA16(ka[x], rb, gacc[x][y]);
    }
  }
  __syncthreads();   // all LDS frag reads done; safe to overlay G

  #pragma unroll
  for (int x = 0; x < 2; x++)
    #pragma unroll
    for (int y = 0; y < 4; y++)
      #pragma unroll
      for (int r = 0; r < 4; r++)
        G[16*(2*wa+x) + 4*(lane >> 4) + r][16*(4*wb+y) + (lane & 15)] = gacc[x][y][r];
  __syncthreads();

  #pragma unroll
  for (int x = 0; x < 2; x++) {
    #pragma unroll
    for (int y = 0; y < 2; y++) {
      #pragma unroll
      for (int r = 0; r < 4; r++) {
        int il = 16*(2*wa+x) + 4*(lane >> 4) + r;
        int jl = 16*(2*wb+y) + (lane & 15);
        float v = cacc[x][y][r] + G[jl][il - jl + 63];
        logits[((size_t)z * NSEQ + i0 + il) * NSEQ + j0 + jl] = v;
      }
    }
  }
}

// ---------------- row softmax f32 -> f16 ----------------
__global__ __launch_bounds__(256) void softmax_k(const float* __restrict__ logits,
                                                 f16* __restrict__ attn) {
  size_t row = blockIdx.x;
  const float* lp = logits + row * NSEQ;
  int tid = threadIdx.x;
  float v[8]; float mx = -3.4e38f;
  #pragma unroll
  for (int u = 0; u < 8; u++) { v[u] = lp[tid + u * 256]; mx = fmaxf(mx, v[u]); }
  #pragma unroll
  for (int off = 32; off >= 1; off >>= 1) mx = fmaxf(mx, __shfl_down(mx, off));
  __shared__ float redm[4], reds[4];
  if ((tid & 63) == 0) redm[tid >> 6] = mx;
  __syncthreads();
  mx = fmaxf(fmaxf(redm[0], redm[1]), fmaxf(redm[2], redm[3]));
  float s = 0.f;
  #pragma unroll
  for (int u = 0; u < 8; u++) { v[u] = expf(v[u] - mx); s += v[u]; }
  #pragma unroll
  for (int off = 32; off >= 1; off >>= 1) s += __shfl_down(s, off);
  if ((tid & 63) == 0) reds[tid >> 6] = s;
  __syncthreads();
  s = reds[0] + reds[1] + reds[2] + reds[3];
  float inv = 1.f / s;
  f16* ap = attn + row * NSEQ;
  #pragma unroll
  for (int u = 0; u < 8; u++) ap[tid + u * 256] = (f16)(v[u] * inv);
}

// ---------------- PV (MFMA f16) ----------------
// TA=0: out[i,d] = sum_j attn[i,j] v[j,d]   (A = attn rows, direct)
// TA=1: out[j,d] = sum_i attn[i,j] v[i,d]   (A = attn^T, transposed stage)
template<int TA>
__global__ __launch_bounds__(256) void pv_k(const f16* __restrict__ attn,
    const float* __restrict__ v, float* __restrict__ oacc, int bh0)
{
  __shared__ f16 As[64][40];   // [out-row][k]
  __shared__ f16 Vs[64][40];   // [d][k]
  int z = blockIdx.y; int bh = bh0 + z; int b = bh >> 3, h = bh & 7;
  int r0 = blockIdx.x * 64;
  int tid = threadIdx.x;
  int w = tid >> 6, lane = tid & 63;
  f32x4 acc[4] = {};
  for (int k0 = 0; k0 < NSEQ; k0 += 32) {
    if constexpr (TA == 0) {
      int row = tid >> 2, c0 = (tid & 3) * 8;
      *(f16x8*)&As[row][c0] =
          *(const f16x8*)&attn[((size_t)z * NSEQ + r0 + row) * NSEQ + k0 + c0];
    } else {
      int kk = tid >> 3, c0 = (tid & 7) * 8;
      f16x8 av = *(const f16x8*)&attn[((size_t)z * NSEQ + k0 + kk) * NSEQ + r0 + c0];
      #pragma unroll
      for (int t = 0; t < 8; t++) As[c0 + t][kk] = av[t];
    }
    int kk = tid >> 3, d0 = (tid & 7) * 8;
    const float* vp = &v[((size_t)bh * NSEQ + k0 + kk) * 64 + d0];
    float4 v0 = *(const float4*)vp, v1 = *(const float4*)(vp + 4);
    Vs[d0+0][kk] = (f16)v0.x; Vs[d0+1][kk] = (f16)v0.y;
    Vs[d0+2][kk] = (f16)v0.z; Vs[d0+3][kk] = (f16)v0.w;
    Vs[d0+4][kk] = (f16)v1.x; Vs[d0+5][kk] = (f16)v1.y;
    Vs[d0+6][kk] = (f16)v1.z; Vs[d0+7][kk] = (f16)v1.w;
    __syncthreads();
    f16x8 af = *(const f16x8*)&As[16*w + (lane & 15)][8*(lane >> 4)];
    #pragma unroll
    for (int nt = 0; nt < 4; nt++) {
      f16x8 vf = *(const f16x8*)&Vs[16*nt + (lane & 15)][8*(lane >> 4)];
      acc[nt] = MFMA16(af, vf, acc[nt]);
    }
    __syncthreads();
  }
  #pragma unroll
  for (int nt = 0; nt < 4; nt++) {
    #pragma unroll
    for (int r = 0; r < 4; r++) {
      int row = r0 + 16*w + 4*(lane >> 4) + r;
      int d = 16*nt + (lane & 15);
      oacc[((size_t)b * NSEQ + row) * 512 + h * 64 + d] = acc[nt][r];
    }
  }
}

extern "C" void kernel_launch(void* const* d_in, const int* in_sizes, int n_in,
                              void* d_out, int out_size, void* d_ws, size_t ws_size,
                              hipStream_t stream) {
  const float* x1   = (const float*)d_in[0];
  const float* x2   = (const float*)d_in[1];
  const float* Wq   = (const float*)d_in[2];
  const float* Wk   = (const float*)d_in[3];
  const float* Wv1  = (const float*)d_in[4];
  const float* Wv2  = (const float*)d_in[5];
  const float* Wrel = (const float*)d_in[6];
  const float* rpb  = (const float*)d_in[7];
  const float* Wo1  = (const float*)d_in[8];
  const float* bo1  = (const float*)d_in[9];
  const float* Wo2  = (const float*)d_in[10];
  const float* bo2  = (const float*)d_in[11];
  float* out = (float*)d_out;

  float* ws = (float*)d_ws;
  size_t off = 0;
  float* pos   = ws + off; off += (size_t)NPOS * 192;
  float* relq  = ws + off; off += (size_t)NH * NPOS * 64;
  float* q     = ws + off; off += (size_t)16 * NSEQ * 64;
  float* kb    = ws + off; off += (size_t)16 * NSEQ * 64;
  float* v1    = ws + off; off += (size_t)16 * NSEQ * 64;
  float* v2    = ws + off; off += (size_t)16 * NSEQ * 64;
  float* o1acc = ws + off; off += (size_t)NBAT * NSEQ * 512;
  float* o2acc = ws + off; off += (size_t)NBAT * NSEQ * 512;
  size_t baseF = off;

  int chunk = 1;
  for (int c = 8; c >= 1; c >>= 1) {
    size_t needB = (baseF + (size_t)c * NSEQ * NSEQ + (size_t)c * NSEQ * NSEQ / 2) * 4;
    if (needB <= ws_size) { chunk = c; break; }
  }
  float* logits = ws + baseF;
  f16* attn = (f16*)(logits + (size_t)chunk * NSEQ * NSEQ);

  pos_embed_k<<<(NPOS + 63) / 64, 64, 0, stream>>>(pos);
  mgemm_k<2><<<dim3(8, 64), 256, 0, stream>>>(pos, Wrel, relq, nullptr, NPOS, 192, 512);
  mgemm_k<0><<<dim3(8, 64), 256, 0, stream>>>(x1, Wq, q, nullptr, NBAT * NSEQ, 1024, 512);
  mgemm_k<1><<<dim3(8, 64), 256, 0, stream>>>(x2, Wk, kb, rpb, NBAT * NSEQ, 512, 512);
  mgemm_k<0><<<dim3(8, 64), 256, 0, stream>>>(x1, Wv1, v1, nullptr, NBAT * NSEQ, 1024, 512);
  mgemm_k<0><<<dim3(8, 64), 256, 0, stream>>>(x2, Wv2, v2, nullptr, NBAT * NSEQ, 512, 512);

  for (int bh0 = 0; bh0 < 16; bh0 += chunk) {
    logits_k<<<dim3(32, 32, chunk), 256, 0, stream>>>(q, kb, relq, logits, bh0);
    softmax_k<<<chunk * NSEQ, 256, 0, stream>>>(logits, attn);
    pv_k<0><<<dim3(32, chunk), 256, 0, stream>>>(attn, v2, o1acc, bh0);
    pv_k<1><<<dim3(32, chunk), 256, 0, stream>>>(attn, v1, o2acc, bh0);
  }

  mgemm_k<3><<<dim3(16, 64), 256, 0, stream>>>(o1acc, Wo1, out, bo1, NBAT * NSEQ, 512, 1024);
  mgemm_k<3><<<dim3(16, 64), 256, 0, stream>>>(o2acc, Wo2, out + (size_t)NBAT * NSEQ * 1024,
                                               bo2, NBAT * NSEQ, 512, 1024);
}

// Round 3
// 529.173 us; speedup vs baseline: 2.9550x; 1.4239x over previous
//
#include <hip/hip_runtime.h>
#include <math.h>

#define NSEQ 2048
#define NPOS 4095   // 2*NSEQ-1
#define NH   8
#define NBAT 2

typedef _Float16 f16;
typedef f16 f16x8 __attribute__((ext_vector_type(8)));
typedef float f32x4 __attribute__((ext_vector_type(4)));

#define MFMA16(a, b, c) __builtin_amdgcn_mfma_f32_16x16x32_f16(a, b, c, 0, 0, 0)

__device__ __forceinline__ f16x8 cvt8(float4 a, float4 b) {
  f16x8 r = {(f16)a.x, (f16)a.y, (f16)a.z, (f16)a.w,
             (f16)b.x, (f16)b.y, (f16)b.z, (f16)b.w};
  return r;
}

// ---------------- positional embedding pos[NPOS][192], one lane per (t,f) ----
__global__ __launch_bounds__(256) void pos_embed_k(float* __restrict__ pos) {
  int t = blockIdx.x * 8 + (threadIdx.x >> 5);
  int f = threadIdx.x & 31;
  if (t >= NPOS) return;
  float dist = (float)(t - (NSEQ - 1));
  float ad = fabsf(dist);
  float sgn = (dist > 0.f) ? 1.f : ((dist < 0.f) ? -1.f : 0.f);
  // gamma pdf feature (double for cancellation safety)
  double mean = 64.0 * (double)(f + 1);       // linspace(64,2048,32)
  double conc = (mean / 32.0) * (mean / 32.0);
  double rate = mean / 1024.0;
  double p = 0.0;
  if (ad > 0.f) {
    double lu = (conc - 1.0) * log((double)ad) - rate * (double)ad;
    double ln = lgamma(conc) - conc * log(rate);
    p = exp(lu - ln);
  }
  float pf = (float)p + 1e-8f;
  float gmax = pf;
  #pragma unroll
  for (int mk = 1; mk <= 16; mk <<= 1) gmax = fmaxf(gmax, __shfl_xor(gmax, mk));
  float fg = pf / gmax;
  float hl = exp2f(3.f + 8.f * (float)f * (1.f / 31.f));  // 2^linspace(3,11,32)
  float fe = exp2f(-ad / hl);
  float cw = exp2f((float)(f + 1)) - 1.f;
  float fc = (cw > ad) ? 1.f : 0.f;
  float* row = pos + (size_t)t * 192;
  row[f]       = fe;       row[32 + f]  = fc;       row[64 + f]  = fg;
  row[96 + f]  = sgn * fe; row[128 + f] = sgn * fc; row[160 + f] = sgn * fg;
}

// ---------------- MFMA f16 GEMM: C[M,N] = A[M,K] * W[K,N] ------------------
// MODE 0: head-split out[(b*NH+h)*NSEQ*64 + row*64 + d]          (q,v1,v2 -> f16)
// MODE 1: head-split, val = val*0.125 + extra[n]                 (kb -> f16)
// MODE 2: relq out[(h*NPOS + m)*64 + d]                          (-> f16)
// MODE 3: plain out[m*Nout+n] = val + extra[n]                   (final, f32)
template<int MODE, typename OT>
__global__ __launch_bounds__(256) void mgemm_k(
    const float* __restrict__ A, const float* __restrict__ W,
    OT* __restrict__ out, const float* __restrict__ extra,
    int M, int K, int Nout)
{
  __shared__ f16 As[64][40];   // [m][k]
  __shared__ f16 Bs[64][40];   // [n][k]
  int tid = threadIdx.x;
  int w = tid >> 6, lane = tid & 63;
  int m0 = blockIdx.y * 64, n0 = blockIdx.x * 64;
  int ar = tid >> 2, ac = (tid & 3) * 8;
  int bk = tid >> 3, bn = (tid & 7) * 8;
  f32x4 acc[4] = {};
  for (int k0 = 0; k0 < K; k0 += 32) {
    float4 a0 = make_float4(0.f,0.f,0.f,0.f), a1 = a0;
    if (m0 + ar < M) {
      const float* ap = &A[(size_t)(m0 + ar) * K + k0 + ac];
      a0 = *(const float4*)ap; a1 = *(const float4*)(ap + 4);
    }
    *(f16x8*)&As[ar][ac] = cvt8(a0, a1);
    const float* bp = &W[(size_t)(k0 + bk) * Nout + n0 + bn];
    float4 b0 = *(const float4*)bp, b1 = *(const float4*)(bp + 4);
    Bs[bn+0][bk] = (f16)b0.x; Bs[bn+1][bk] = (f16)b0.y;
    Bs[bn+2][bk] = (f16)b0.z; Bs[bn+3][bk] = (f16)b0.w;
    Bs[bn+4][bk] = (f16)b1.x; Bs[bn+5][bk] = (f16)b1.y;
    Bs[bn+6][bk] = (f16)b1.z; Bs[bn+7][bk] = (f16)b1.w;
    __syncthreads();
    f16x8 af = *(const f16x8*)&As[16*w + (lane & 15)][8*(lane >> 4)];
    #pragma unroll
    for (int nt = 0; nt < 4; nt++) {
      f16x8 bf = *(const f16x8*)&Bs[16*nt + (lane & 15)][8*(lane >> 4)];
      acc[nt] = MFMA16(af, bf, acc[nt]);
    }
    __syncthreads();
  }
  #pragma unroll
  for (int nt = 0; nt < 4; nt++) {
    #pragma unroll
    for (int r = 0; r < 4; r++) {
      int m = m0 + 16*w + 4*(lane >> 4) + r;
      int n = n0 + 16*nt + (lane & 15);
      if (m >= M) continue;
      float v = acc[nt][r];
      if constexpr (MODE == 0 || MODE == 1) {
        if constexpr (MODE == 1) v = v * 0.125f + extra[n];
        int b = m >> 11, row = m & (NSEQ - 1), h = n >> 6, d = n & 63;
        out[(((size_t)(b * NH + h)) * NSEQ + row) * 64 + d] = (OT)v;
      } else if constexpr (MODE == 2) {
        int h = n >> 6, d = n & 63;
        out[((size_t)h * NPOS + m) * 64 + d] = (OT)v;
      } else {
        out[(size_t)m * Nout + n] = (OT)(v + extra[n]);
      }
    }
  }
}

// ---------------- fused logits + softmax (2-pass flash) ----------------
// l[i,j] = sum_d q[i,d]*kb[j,d] + G[j, i-j+63],  G[j,n] = kb[j]·relq[nbase+n]
// pass 0: row max only. pass 1: p=exp(l-m) f16 -> attn (unnormalized), inv_s.
__global__ __launch_bounds__(256) void attn_k(
    const f16* __restrict__ q, const f16* __restrict__ kb,
    const f16* __restrict__ relq, f16* __restrict__ attn,
    float* __restrict__ inv_s, int bh0)
{
  __shared__ f16 Qs[64][72];
  __shared__ f16 KBs[64][72];
  __shared__ f16 Rs[128][72];
  __shared__ float G[64][132];      // pass-1 also overlaid as P f16 [64][68]
  __shared__ float red[64][2];
  int z = blockIdx.y; int bh = bh0 + z; int h = bh & 7;
  int i0 = blockIdx.x * 64;
  int tid = threadIdx.x;
  int w = tid >> 6, lane = tid & 63;
  int wa = w >> 1, wb = w & 1;
  int lr = lane >> 4, lc = lane & 15;
  {
    int row = tid >> 2, c0 = (tid & 3) * 16;
    const f16* qp = q + ((size_t)bh * NSEQ + i0 + row) * 64 + c0;
    *(f16x8*)&Qs[row][c0]     = *(const f16x8*)qp;
    *(f16x8*)&Qs[row][c0 + 8] = *(const f16x8*)(qp + 8);
  }
  __syncthreads();
  f16x8 qa[2][2];
  #pragma unroll
  for (int kh = 0; kh < 2; kh++)
    #pragma unroll
    for (int x = 0; x < 2; x++)
      qa[kh][x] = *(const f16x8*)&Qs[16*(2*wa+x) + lc][32*kh + 8*lr];

  float pmax[2][4], m_final[2][4], ssum[2][4];
  #pragma unroll
  for (int x = 0; x < 2; x++)
    #pragma unroll
    for (int r = 0; r < 4; r++) { pmax[x][r] = -1e30f; ssum[x][r] = 0.f; }

  for (int pass = 0; pass < 2; pass++) {
    for (int jt = 0; jt < 32; jt++) {
      int j0 = jt * 64;
      {
        int row = tid >> 2, c0 = (tid & 3) * 16;
        const f16* kp = kb + ((size_t)bh * NSEQ + j0 + row) * 64 + c0;
        *(f16x8*)&KBs[row][c0]     = *(const f16x8*)kp;
        *(f16x8*)&KBs[row][c0 + 8] = *(const f16x8*)(kp + 8);
        int rr = tid >> 1, rd = (tid & 1) * 32;
        int nbase = (NSEQ - 1) + i0 - j0 - 63;
        const f16* rp = relq + ((size_t)h * NPOS + nbase + rr) * 64 + rd;
        #pragma unroll
        for (int u = 0; u < 4; u++)
          *(f16x8*)&Rs[rr][rd + u*8] = *(const f16x8*)(rp + u*8);
      }
      __syncthreads();
      f32x4 cacc[2][2] = {}; f32x4 gacc[2][4] = {};
      #pragma unroll
      for (int kh = 0; kh < 2; kh++) {
        int kof = 32*kh + 8*lr;
        f16x8 ka[2], kbf[2];
        #pragma unroll
        for (int x = 0; x < 2; x++) {
          ka[x]  = *(const f16x8*)&KBs[16*(2*wa+x) + lc][kof];
          kbf[x] = *(const f16x8*)&KBs[16*(2*wb+x) + lc][kof];
        }
        #pragma unroll
        for (int x = 0; x < 2; x++)
          #pragma unroll
          for (int y = 0; y < 2; y++)
            cacc[x][y] = MFMA16(qa[kh][x], kbf[y], cacc[x][y]);
        #pragma unroll
        for (int y = 0; y < 4; y++) {
          f16x8 rb = *(const f16x8*)&Rs[16*(4*wb+y) + lc][kof];
          #pragma unroll
          for (int x = 0; x < 2; x++)
            gacc[x][y] = MFMA16(ka[x], rb, gacc[x][y]);
        }
      }
      __syncthreads();
      #pragma unroll
      for (int x = 0; x < 2; x++)
        #pragma unroll
        for (int y = 0; y < 4; y++)
          #pragma unroll
          for (int r = 0; r < 4; r++)
            G[16*(2*wa+x) + 4*lr + r][16*(4*wb+y) + lc] = gacc[x][y][r];
      __syncthreads();
      if (pass == 0) {
        #pragma unroll
        for (int x = 0; x < 2; x++)
          #pragma unroll
          for (int y = 0; y < 2; y++)
            #pragma unroll
            for (int r = 0; r < 4; r++) {
              int il = 16*(2*wa+x) + 4*lr + r;
              int jl = 16*(2*wb+y) + lc;
              float v = cacc[x][y][r] + G[jl][il - jl + 63];
              pmax[x][r] = fmaxf(pmax[x][r], v);
            }
      } else {
        f16* P = (f16*)&G[0][0];   // [64][68]
        float pv[2][2][4];
        #pragma unroll
        for (int x = 0; x < 2; x++)
          #pragma unroll
          for (int y = 0; y < 2; y++)
            #pragma unroll
            for (int r = 0; r < 4; r++) {
              int il = 16*(2*wa+x) + 4*lr + r;
              int jl = 16*(2*wb+y) + lc;
              float v = cacc[x][y][r] + G[jl][il - jl + 63];
              float p = expf(v - m_final[x][r]);
              ssum[x][r] += p;
              pv[x][y][r] = p;
            }
        __syncthreads();   // all gather reads done before overlay write
        #pragma unroll
        for (int x = 0; x < 2; x++)
          #pragma unroll
          for (int y = 0; y < 2; y++)
            #pragma unroll
            for (int r = 0; r < 4; r++)
              P[(16*(2*wa+x) + 4*lr + r) * 68 + 16*(2*wb+y) + lc] = (f16)pv[x][y][r];
        __syncthreads();
        int row = tid >> 2, c0 = (tid & 3) * 16;
        f16* ap = attn + ((size_t)z * NSEQ + i0 + row) * NSEQ + j0 + c0;
        *(f16x8*)ap       = *(const f16x8*)&P[row * 68 + c0];
        *(f16x8*)(ap + 8) = *(const f16x8*)&P[row * 68 + c0 + 8];
      }
    }
    if (pass == 0) {
      #pragma unroll
      for (int x = 0; x < 2; x++)
        #pragma unroll
        for (int r = 0; r < 4; r++) {
          float m = pmax[x][r];
          #pragma unroll
          for (int mk = 1; mk <= 8; mk <<= 1) m = fmaxf(m, __shfl_xor(m, mk));
          if (lc == 0) red[16*(2*wa+x) + 4*lr + r][wb] = m;
        }
      __syncthreads();
      #pragma unroll
      for (int x = 0; x < 2; x++)
        #pragma unroll
        for (int r = 0; r < 4; r++)
          m_final[x][r] = fmaxf(red[16*(2*wa+x) + 4*lr + r][0],
                                red[16*(2*wa+x) + 4*lr + r][1]);
      __syncthreads();
    }
  }
  // final sum reduce -> inv_s
  #pragma unroll
  for (int x = 0; x < 2; x++)
    #pragma unroll
    for (int r = 0; r < 4; r++) {
      float s = ssum[x][r];
      #pragma unroll
      for (int mk = 1; mk <= 8; mk <<= 1) s += __shfl_xor(s, mk);
      if (lc == 0) red[16*(2*wa+x) + 4*lr + r][wb] = s;
    }
  __syncthreads();
  if (wb == 0 && lc == 0) {
    #pragma unroll
    for (int x = 0; x < 2; x++)
      #pragma unroll
      for (int r = 0; r < 4; r++) {
        int il = 16*(2*wa+x) + 4*lr + r;
        inv_s[(size_t)bh * NSEQ + i0 + il] = 1.f / (red[il][0] + red[il][1]);
      }
  }
}

// ---------------- PV (MFMA f16), attn holds unnormalized p ----------------
// TA=0: out1[i,d] = inv_s[i] * sum_j p[i,j] v2[j,d]     (scale epilogue)
// TA=1: out2[j,d] = sum_i p[i,j] * (inv_s[i] v1[i,d])   (scale V staging)
template<int TA>
__global__ __launch_bounds__(256) void pv_k(const f16* __restrict__ attn,
    const f16* __restrict__ v, const float* __restrict__ inv_s,
    float* __restrict__ oacc, int bh0)
{
  __shared__ f16 As[64][40];
  __shared__ f16 Vs[64][40];
  int z = blockIdx.y; int bh = bh0 + z; int b = bh >> 3, h = bh & 7;
  int r0 = blockIdx.x * 64;
  int tid = threadIdx.x;
  int w = tid >> 6, lane = tid & 63;
  f32x4 acc[4] = {};
  for (int k0 = 0; k0 < NSEQ; k0 += 32) {
    if constexpr (TA == 0) {
      int row = tid >> 2, c0 = (tid & 3) * 8;
      *(f16x8*)&As[row][c0] =
          *(const f16x8*)&attn[((size_t)z * NSEQ + r0 + row) * NSEQ + k0 + c0];
    } else {
      int kk = tid >> 3, c0 = (tid & 7) * 8;
      f16x8 av = *(const f16x8*)&attn[((size_t)z * NSEQ + k0 + kk) * NSEQ + r0 + c0];
      #pragma unroll
      for (int t = 0; t < 8; t++) As[c0 + t][kk] = av[t];
    }
    int kk = tid >> 3, d0 = (tid & 7) * 8;
    f16x8 vv = *(const f16x8*)&v[((size_t)bh * NSEQ + k0 + kk) * 64 + d0];
    if constexpr (TA == 1) {
      float sc = inv_s[(size_t)bh * NSEQ + k0 + kk];
      #pragma unroll
      for (int t = 0; t < 8; t++) Vs[d0 + t][kk] = (f16)((float)vv[t] * sc);
    } else {
      #pragma unroll
      for (int t = 0; t < 8; t++) Vs[d0 + t][kk] = vv[t];
    }
    __syncthreads();
    f16x8 af = *(const f16x8*)&As[16*w + (lane & 15)][8*(lane >> 4)];
    #pragma unroll
    for (int nt = 0; nt < 4; nt++) {
      f16x8 vf = *(const f16x8*)&Vs[16*nt + (lane & 15)][8*(lane >> 4)];
      acc[nt] = MFMA16(af, vf, acc[nt]);
    }
    __syncthreads();
  }
  float rs[4];
  #pragma unroll
  for (int r = 0; r < 4; r++)
    rs[r] = (TA == 0) ? inv_s[(size_t)bh * NSEQ + r0 + 16*w + 4*(lane >> 4) + r] : 1.f;
  #pragma unroll
  for (int nt = 0; nt < 4; nt++) {
    #pragma unroll
    for (int r = 0; r < 4; r++) {
      int row = r0 + 16*w + 4*(lane >> 4) + r;
      int d = 16*nt + (lane & 15);
      oacc[((size_t)b * NSEQ + row) * 512 + h * 64 + d] = acc[nt][r] * rs[r];
    }
  }
}

extern "C" void kernel_launch(void* const* d_in, const int* in_sizes, int n_in,
                              void* d_out, int out_size, void* d_ws, size_t ws_size,
                              hipStream_t stream) {
  const float* x1   = (const float*)d_in[0];
  const float* x2   = (const float*)d_in[1];
  const float* Wq   = (const float*)d_in[2];
  const float* Wk   = (const float*)d_in[3];
  const float* Wv1  = (const float*)d_in[4];
  const float* Wv2  = (const float*)d_in[5];
  const float* Wrel = (const float*)d_in[6];
  const float* rpb  = (const float*)d_in[7];
  const float* Wo1  = (const float*)d_in[8];
  const float* bo1  = (const float*)d_in[9];
  const float* Wo2  = (const float*)d_in[10];
  const float* bo2  = (const float*)d_in[11];
  float* out = (float*)d_out;

  char* base = (char*)d_ws;
  size_t off = 0;
  auto alloc = [&](size_t bytes) -> void* {
    void* p = base + off; off += (bytes + 255) & ~(size_t)255; return p;
  };
  float* pos   = (float*)alloc((size_t)NPOS * 192 * 4);
  f16*   relq  = (f16*)  alloc((size_t)NH * NPOS * 64 * 2);
  f16*   qh    = (f16*)  alloc((size_t)16 * NSEQ * 64 * 2);
  f16*   kbh   = (f16*)  alloc((size_t)16 * NSEQ * 64 * 2);
  f16*   v1h   = (f16*)  alloc((size_t)16 * NSEQ * 64 * 2);
  f16*   v2h   = (f16*)  alloc((size_t)16 * NSEQ * 64 * 2);
  float* o1acc = (float*)alloc((size_t)NBAT * NSEQ * 512 * 4);
  float* o2acc = (float*)alloc((size_t)NBAT * NSEQ * 512 * 4);
  float* invs  = (float*)alloc((size_t)16 * NSEQ * 4);
  size_t baseB = off;

  int chunk = 1;
  for (int c = 16; c >= 1; c >>= 1) {
    size_t needB = baseB + (size_t)c * NSEQ * NSEQ * 2;
    if (needB <= ws_size) { chunk = c; break; }
  }
  f16* attn = (f16*)(base + baseB);

  pos_embed_k<<<(NPOS + 7) / 8, 256, 0, stream>>>(pos);
  mgemm_k<2, f16><<<dim3(8, 64), 256, 0, stream>>>(pos, Wrel, relq, nullptr, NPOS, 192, 512);
  mgemm_k<0, f16><<<dim3(8, 64), 256, 0, stream>>>(x1, Wq, qh, nullptr, NBAT * NSEQ, 1024, 512);
  mgemm_k<1, f16><<<dim3(8, 64), 256, 0, stream>>>(x2, Wk, kbh, rpb, NBAT * NSEQ, 512, 512);
  mgemm_k<0, f16><<<dim3(8, 64), 256, 0, stream>>>(x1, Wv1, v1h, nullptr, NBAT * NSEQ, 1024, 512);
  mgemm_k<0, f16><<<dim3(8, 64), 256, 0, stream>>>(x2, Wv2, v2h, nullptr, NBAT * NSEQ, 512, 512);

  for (int bh0 = 0; bh0 < 16; bh0 += chunk) {
    attn_k<<<dim3(32, chunk), 256, 0, stream>>>(qh, kbh, relq, attn, invs, bh0);
    pv_k<0><<<dim3(32, chunk), 256, 0, stream>>>(attn, v2h, invs, o1acc, bh0);
    pv_k<1><<<dim3(32, chunk), 256, 0, stream>>>(attn, v1h, invs, o2acc, bh0);
  }

  mgemm_k<3, float><<<dim3(16, 64), 256, 0, stream>>>(o1acc, Wo1, out, bo1, NBAT * NSEQ, 512, 1024);
  mgemm_k<3, float><<<dim3(16, 64), 256, 0, stream>>>(o2acc, Wo2, out + (size_t)NBAT * NSEQ * 1024,
                                                      bo2, NBAT * NSEQ, 512, 1024);
}

// Round 5
// 436.498 us; speedup vs baseline: 3.5824x; 1.2123x over previous
//
#include <hip/hip_runtime.h>
#include <math.h>

#define NSEQ 2048
#define NPOS 4095   // 2*NSEQ-1
#define NH   8

typedef _Float16 f16;
typedef f16 f16x8 __attribute__((ext_vector_type(8)));
typedef f16 f16x4 __attribute__((ext_vector_type(4)));
typedef float f32x4 __attribute__((ext_vector_type(4)));

#define MFMA16(a,b,c) __builtin_amdgcn_mfma_f32_16x16x32_f16(a,b,c,0,0,0)

__device__ __forceinline__ f16x8 cvt8(float4 a, float4 b) {
  f16x8 r = {(f16)a.x, (f16)a.y, (f16)a.z, (f16)a.w,
             (f16)b.x, (f16)b.y, (f16)b.z, (f16)b.w};
  return r;
}

// ---------------- positional embedding pos[NPOS][192], one lane per (t,f) ----
__global__ __launch_bounds__(256) void pos_embed_k(float* __restrict__ pos) {
  int t = blockIdx.x * 8 + (threadIdx.x >> 5);
  int f = threadIdx.x & 31;
  if (t >= NPOS) return;
  float dist = (float)(t - (NSEQ - 1));
  float ad = fabsf(dist);
  float sgn = (dist > 0.f) ? 1.f : ((dist < 0.f) ? -1.f : 0.f);
  double mean = 64.0 * (double)(f + 1);       // linspace(64,2048,32)
  double conc = (mean / 32.0) * (mean / 32.0);
  double rate = mean / 1024.0;
  double p = 0.0;
  if (ad > 0.f) {
    double lu = (conc - 1.0) * log((double)ad) - rate * (double)ad;
    double ln = lgamma(conc) - conc * log(rate);
    p = exp(lu - ln);
  }
  float pf = (float)p + 1e-8f;
  float gmax = pf;
  #pragma unroll
  for (int mk = 1; mk <= 16; mk <<= 1) gmax = fmaxf(gmax, __shfl_xor(gmax, mk));
  float fg = pf / gmax;
  float hl = exp2f(3.f + 8.f * (float)f * (1.f / 31.f));
  float fe = exp2f(-ad / hl);
  float cw = exp2f((float)(f + 1)) - 1.f;
  float fc = (cw > ad) ? 1.f : 0.f;
  float* row = pos + (size_t)t * 192;
  row[f]       = fe;       row[32 + f]  = fc;       row[64 + f]  = fg;
  row[96 + f]  = sgn * fe; row[128 + f] = sgn * fc; row[160 + f] = sgn * fg;
}

// ---------------- relq = pos @ Wrel -> f16 [h][NPOS][64] ----------------
__global__ __launch_bounds__(256) void relq_k(
    const float* __restrict__ A, const float* __restrict__ W, f16* __restrict__ relq)
{
  __shared__ f16 As[64][56];
  __shared__ f16 Bs[64][56];
  int tid = threadIdx.x, w = tid >> 6, lane = tid & 63, lr = lane >> 4, lc = lane & 15;
  int m0 = blockIdx.y * 64, n0 = blockIdx.x * 64;
  int ar = tid >> 2, ac = (tid & 3) * 8;
  int bk = tid >> 3, bn = (tid & 7) * 8;
  f32x4 acc[4] = {};
  for (int k0 = 0; k0 < 192; k0 += 32) {
    float4 a0 = make_float4(0.f,0.f,0.f,0.f), a1 = a0;
    if (m0 + ar < NPOS) {
      const float* ap = &A[(size_t)(m0 + ar) * 192 + k0 + ac];
      a0 = *(const float4*)ap; a1 = *(const float4*)(ap + 4);
    }
    *(f16x8*)&As[ar][ac] = cvt8(a0, a1);
    const float* bp = &W[(size_t)(k0 + bk) * 512 + n0 + bn];
    float4 b0 = *(const float4*)bp, b1 = *(const float4*)(bp + 4);
    f16 bv[8] = {(f16)b0.x,(f16)b0.y,(f16)b0.z,(f16)b0.w,(f16)b1.x,(f16)b1.y,(f16)b1.z,(f16)b1.w};
    #pragma unroll
    for (int tt = 0; tt < 8; tt++) { int t = (tt + bk) & 7; Bs[bn + t][bk] = bv[t]; }
    __syncthreads();
    f16x8 af = *(const f16x8*)&As[16*w + lc][8*lr];
    #pragma unroll
    for (int nt = 0; nt < 4; nt++) {
      f16x8 bf = *(const f16x8*)&Bs[16*nt + lc][8*lr];
      acc[nt] = MFMA16(af, bf, acc[nt]);
    }
    __syncthreads();
  }
  #pragma unroll
  for (int nt = 0; nt < 4; nt++)
    #pragma unroll
    for (int r = 0; r < 4; r++) {
      int m = m0 + 16*w + 4*lr + r;
      if (m >= NPOS) continue;
      int nn = n0 + 16*nt + lc;
      relq[((size_t)(nn >> 6) * NPOS + m) * 64 + (nn & 63)] = (f16)acc[nt][r];
    }
}

// ---------------- fused input projections: A[4096,KD] x (W1|W2)[KD,512] ----
// n0g<512 -> O1 (optionally *0.125+rpb), else O2. head-split f16 out.
template<int KD, bool SC1>
__global__ __launch_bounds__(256) void projx_k(
    const float* __restrict__ A, const float* __restrict__ W1, const float* __restrict__ W2,
    f16* __restrict__ O1, f16* __restrict__ O2, const float* __restrict__ rpb)
{
  __shared__ f16 As[64][56];
  __shared__ f16 Bs[64][56];
  int tid = threadIdx.x, w = tid >> 6, lane = tid & 63, lr = lane >> 4, lc = lane & 15;
  int m0 = blockIdx.y * 64, n0g = blockIdx.x * 64;
  bool first = (n0g < 512);
  const float* W = first ? W1 : W2;
  f16* O = first ? O1 : O2;
  int n0 = n0g & 511;
  int ar = tid >> 2, ac = (tid & 3) * 8;
  int bk = tid >> 3, bn = (tid & 7) * 8;
  f32x4 acc[4] = {};
  for (int k0 = 0; k0 < KD; k0 += 32) {
    const float* ap = &A[(size_t)(m0 + ar) * KD + k0 + ac];
    *(f16x8*)&As[ar][ac] = cvt8(*(const float4*)ap, *(const float4*)(ap + 4));
    const float* bp = &W[(size_t)(k0 + bk) * 512 + n0 + bn];
    float4 b0 = *(const float4*)bp, b1 = *(const float4*)(bp + 4);
    f16 bv[8] = {(f16)b0.x,(f16)b0.y,(f16)b0.z,(f16)b0.w,(f16)b1.x,(f16)b1.y,(f16)b1.z,(f16)b1.w};
    #pragma unroll
    for (int tt = 0; tt < 8; tt++) { int t = (tt + bk) & 7; Bs[bn + t][bk] = bv[t]; }
    __syncthreads();
    f16x8 af = *(const f16x8*)&As[16*w + lc][8*lr];
    #pragma unroll
    for (int nt = 0; nt < 4; nt++) {
      f16x8 bf = *(const f16x8*)&Bs[16*nt + lc][8*lr];
      acc[nt] = MFMA16(af, bf, acc[nt]);
    }
    __syncthreads();
  }
  #pragma unroll
  for (int nt = 0; nt < 4; nt++)
    #pragma unroll
    for (int r = 0; r < 4; r++) {
      int m = m0 + 16*w + 4*lr + r;
      int nn = n0 + 16*nt + lc;
      float vv = acc[nt][r];
      if (SC1 && first) vv = vv * 0.125f + rpb[nn];
      O[(((size_t)((m >> 11) * NH + (nn >> 6))) * NSEQ + (m & (NSEQ - 1))) * 64 + (nn & 63)] = (f16)vv;
    }
}

// ---------------- fused output projections ----------------
__global__ __launch_bounds__(256) void outproj_k(
    const f16* __restrict__ o1, const f16* __restrict__ o2,
    const float* __restrict__ Wo1, const float* __restrict__ Wo2,
    const float* __restrict__ bo1, const float* __restrict__ bo2,
    float* __restrict__ out)
{
  __shared__ f16 As[64][56];
  __shared__ f16 Bs[64][56];
  int by = blockIdx.y;
  bool first = (by < 64);
  const f16* A = first ? o1 : o2;
  const float* W = first ? Wo1 : Wo2;
  const float* bias = first ? bo1 : bo2;
  float* O = out + (first ? 0 : (size_t)4096 * 1024);
  int tid = threadIdx.x, w = tid >> 6, lane = tid & 63, lr = lane >> 4, lc = lane & 15;
  int m0 = (by & 63) * 64, n0 = blockIdx.x * 64;
  int ar = tid >> 2, ac = (tid & 3) * 8;
  int bk = tid >> 3, bn = (tid & 7) * 8;
  f32x4 acc[4] = {};
  for (int k0 = 0; k0 < 512; k0 += 32) {
    *(f16x8*)&As[ar][ac] = *(const f16x8*)&A[(size_t)(m0 + ar) * 512 + k0 + ac];
    const float* bp = &W[(size_t)(k0 + bk) * 1024 + n0 + bn];
    float4 b0 = *(const float4*)bp, b1 = *(const float4*)(bp + 4);
    f16 bv[8] = {(f16)b0.x,(f16)b0.y,(f16)b0.z,(f16)b0.w,(f16)b1.x,(f16)b1.y,(f16)b1.z,(f16)b1.w};
    #pragma unroll
    for (int tt = 0; tt < 8; tt++) { int t = (tt + bk) & 7; Bs[bn + t][bk] = bv[t]; }
    __syncthreads();
    f16x8 af = *(const f16x8*)&As[16*w + lc][8*lr];
    #pragma unroll
    for (int nt = 0; nt < 4; nt++) {
      f16x8 bf = *(const f16x8*)&Bs[16*nt + lc][8*lr];
      acc[nt] = MFMA16(af, bf, acc[nt]);
    }
    __syncthreads();
  }
  #pragma unroll
  for (int nt = 0; nt < 4; nt++)
    #pragma unroll
    for (int r = 0; r < 4; r++) {
      int m = m0 + 16*w + 4*lr + r;
      int n = n0 + 16*nt + lc;
      O[(size_t)m * 1024 + n] = acc[nt][r] + bias[n];
    }
}

// ---------------- fused logits + one-pass online softmax ----------------
// l[i,j] = q[i]·kb[j] + G[j, i-j+63];  G[j,n] = kb[j]·relq[nbase+n]
// writes P = exp(l - m_jt) (f16) and fac[i][jt] = exp(m_jt - m_fin)/sum
// LDS layout (45184 B total):
//   [0,9216)      Qs[64][72]   (prologue only) / G2[64][68] overlay (8704 B)
//   [9216,18432)  KBs[64][72]  / Pw overlay: wave w at +w*2304, [16][72]
//   [18432,36864) Rs[128][72]
//   [36864,45184) m_lds[32][65] f32
__global__ __launch_bounds__(256) void attn_k(
    const f16* __restrict__ q, const f16* __restrict__ kb,
    const f16* __restrict__ relq, f16* __restrict__ attn,
    float* __restrict__ fac, int bh0)
{
  __shared__ char smem[45184];
  f16 (*Qs)[72]  = (f16(*)[72])smem;
  f16 (*KBs)[72] = (f16(*)[72])(smem + 9216);
  f16 (*Rs)[72]  = (f16(*)[72])(smem + 18432);
  f16 (*G2)[68]  = (f16(*)[68])smem;                  // overlay Qs
  float (*m_lds)[65] = (float(*)[65])(smem + 36864);
  int z = blockIdx.y, bh = bh0 + z, h = bh & 7;
  int i0 = blockIdx.x * 64;
  int tid = threadIdx.x, w = tid >> 6, lane = tid & 63;
  int lr = lane >> 4, lc = lane & 15;
  f16 (*Pw)[72] = (f16(*)[72])(smem + 9216 + w * 2304);  // per-wave [16][72] in KBs region

  {
    int row = tid >> 2, c0 = (tid & 3) * 16;
    const f16* qp = q + ((size_t)bh * NSEQ + i0 + row) * 64 + c0;
    *(f16x8*)&Qs[row][c0]     = *(const f16x8*)qp;
    *(f16x8*)&Qs[row][c0 + 8] = *(const f16x8*)(qp + 8);
  }
  __syncthreads();
  f16x8 qa0 = *(const f16x8*)&Qs[16*w + lc][8*lr];
  f16x8 qa1 = *(const f16x8*)&Qs[16*w + lc][32 + 8*lr];

  float m_run[4], ssum[4];
  #pragma unroll
  for (int r = 0; r < 4; r++) { m_run[r] = -1e30f; ssum[r] = 0.f; }

  for (int jt = 0; jt < 32; jt++) {
    int j0 = jt * 64;
    {
      int row = tid >> 2, c0 = (tid & 3) * 16;
      const f16* kp = kb + ((size_t)bh * NSEQ + j0 + row) * 64 + c0;
      *(f16x8*)&KBs[row][c0]     = *(const f16x8*)kp;
      *(f16x8*)&KBs[row][c0 + 8] = *(const f16x8*)(kp + 8);
      int rr = tid >> 1, rd = (tid & 1) * 32;
      int nbase = (NSEQ - 1) + i0 - j0 - 63;
      const f16* rp = relq + ((size_t)h * NPOS + nbase + rr) * 64 + rd;
      #pragma unroll
      for (int u = 0; u < 4; u++)
        *(f16x8*)&Rs[rr][rd + u*8] = *(const f16x8*)(rp + u*8);
    }
    __syncthreads();   // s1: staging visible (also orders prologue Qs reads vs G2 writes)
    f32x4 cacc[4];
    f16x8 ka0 = {}, ka1 = {};
    #pragma unroll
    for (int y = 0; y < 4; y++) {
      f16x8 b0 = *(const f16x8*)&KBs[16*y + lc][8*lr];
      f16x8 b1 = *(const f16x8*)&KBs[16*y + lc][32 + 8*lr];
      f32x4 t = {};
      t = MFMA16(qa0, b0, t);
      t = MFMA16(qa1, b1, t);
      cacc[y] = t;
      if (y == w) { ka0 = b0; ka1 = b1; }
    }
    #pragma unroll
    for (int g = 0; g < 8; g++) {
      f32x4 ga = {};
      ga = MFMA16(ka0, *(const f16x8*)&Rs[16*g + lc][8*lr], ga);
      ga = MFMA16(ka1, *(const f16x8*)&Rs[16*g + lc][32 + 8*lr], ga);
      int jj = 16*w + 4*lr;
      #pragma unroll
      for (int r = 0; r < 4; r++) {
        int ii = 16*g + lc + jj + r - 63;   // i = n + j - 63
        if ((unsigned)ii < 64u) G2[jj + r][ii] = (f16)ga[r];
      }
    }
    __syncthreads();   // s2: G2 complete; KBs frag reads done -> Pw overlay safe
    float l[4][4];
    #pragma unroll
    for (int y = 0; y < 4; y++) {
      f16x4 gv = *(const f16x4*)&G2[16*y + lc][16*w + 4*lr];
      #pragma unroll
      for (int r = 0; r < 4; r++) l[y][r] = cacc[y][r] + (float)gv[r];
    }
    #pragma unroll
    for (int r = 0; r < 4; r++) {
      float tm = fmaxf(fmaxf(l[0][r], l[1][r]), fmaxf(l[2][r], l[3][r]));
      #pragma unroll
      for (int mk = 1; mk <= 8; mk <<= 1) tm = fmaxf(tm, __shfl_xor(tm, mk));
      float mnew = fmaxf(m_run[r], tm);
      ssum[r] *= __expf(m_run[r] - mnew);
      m_run[r] = mnew;
      float ps = 0.f;
      #pragma unroll
      for (int y = 0; y < 4; y++) {
        float p = __expf(l[y][r] - mnew);
        ps += p;
        Pw[4*lr + r][16*y + lc] = (f16)p;
      }
      ssum[r] += ps;
      if (lc == 0) m_lds[jt][16*w + 4*lr + r] = mnew;
    }
    __syncthreads();   // s3: Pw writes complete (cross-lane visibility)
    {
      int prow = lane >> 2, pc0 = (lane & 3) * 16;
      f16* ap = attn + ((size_t)z * NSEQ + i0 + 16*w + prow) * NSEQ + j0 + pc0;
      *(f16x8*)ap       = *(const f16x8*)&Pw[prow][pc0];
      *(f16x8*)(ap + 8) = *(const f16x8*)&Pw[prow][pc0 + 8];
    }
    __syncthreads();   // s4: Pw/G2 reads done -> next tile may restage
  }
  // epilogue: fac[i][jt] = exp(m_jt - m_fin) / sum
  #pragma unroll
  for (int r = 0; r < 4; r++) {
    float s = ssum[r];
    #pragma unroll
    for (int mk = 1; mk <= 8; mk <<= 1) s += __shfl_xor(s, mk);
    int il = 16*w + 4*lr + r;
    float mf = m_run[r];
    float invs = 1.f / s;
    #pragma unroll
    for (int jtb = 0; jtb < 2; jtb++) {
      int jt = jtb * 16 + lc;
      float fv = __expf(m_lds[jt][il] - mf) * invs;
      fac[((size_t)z * NSEQ + i0 + il) * 32 + jt] = fv;
    }
  }
}

// ---------------- PV (MFMA f16), P unnormalized + fac fold ----------------
// TA=0: out1[i,d] = sum_jt fac[i][jt] sum_j P[i,j] v2[j,d]
// TA=1: out2[j,d] = sum_i (fac[i][jt(j)] P[i,j]) v1[i,d]
template<int TA>
__global__ __launch_bounds__(256) void pv_k(const f16* __restrict__ attn,
    const f16* __restrict__ v, const float* __restrict__ fac,
    f16* __restrict__ oacc, int bh0)
{
  __shared__ f16 As[64][56];
  __shared__ f16 Vs[64][56];
  int z = blockIdx.y, bh = bh0 + z, b = bh >> 3, h = bh & 7;
  int r0 = blockIdx.x * 64;
  int tid = threadIdx.x, w = tid >> 6, lane = tid & 63;
  int lr = lane >> 4, lc = lane & 15;
  f32x4 acc[4] = {};
  for (int k0 = 0; k0 < NSEQ; k0 += 32) {
    if constexpr (TA == 0) {
      int row = tid >> 2, c0 = (tid & 3) * 8;
      f16x8 av = *(const f16x8*)&attn[((size_t)z * NSEQ + r0 + row) * NSEQ + k0 + c0];
      f16 sc = (f16)fac[((size_t)z * NSEQ + r0 + row) * 32 + (k0 >> 6)];
      f16x8 sv;
      #pragma unroll
      for (int t = 0; t < 8; t++) sv[t] = av[t] * sc;
      *(f16x8*)&As[row][c0] = sv;
    } else {
      int kk = tid >> 3, c0 = (tid & 7) * 8;
      f16x8 av = *(const f16x8*)&attn[((size_t)z * NSEQ + k0 + kk) * NSEQ + r0 + c0];
      f16 sc = (f16)fac[((size_t)z * NSEQ + k0 + kk) * 32 + (r0 >> 6)];
      #pragma unroll
      for (int tt = 0; tt < 8; tt++) { int t = (tt + kk) & 7; As[c0 + t][kk] = av[t] * sc; }
    }
    int kk = tid >> 3, d0 = (tid & 7) * 8;
    f16x8 vv = *(const f16x8*)&v[((size_t)bh * NSEQ + k0 + kk) * 64 + d0];
    #pragma unroll
    for (int tt = 0; tt < 8; tt++) { int t = (tt + kk) & 7; Vs[d0 + t][kk] = vv[t]; }
    __syncthreads();
    f16x8 af = *(const f16x8*)&As[16*w + lc][8*lr];
    #pragma unroll
    for (int nt = 0; nt < 4; nt++) {
      f16x8 vf = *(const f16x8*)&Vs[16*nt + lc][8*lr];
      acc[nt] = MFMA16(af, vf, acc[nt]);
    }
    __syncthreads();
  }
  #pragma unroll
  for (int nt = 0; nt < 4; nt++)
    #pragma unroll
    for (int r = 0; r < 4; r++) {
      int row = r0 + 16*w + 4*lr + r;
      oacc[((size_t)b * NSEQ + row) * 512 + h * 64 + 16*nt + lc] = (f16)acc[nt][r];
    }
}

extern "C" void kernel_launch(void* const* d_in, const int* in_sizes, int n_in,
                              void* d_out, int out_size, void* d_ws, size_t ws_size,
                              hipStream_t stream) {
  const float* x1   = (const float*)d_in[0];
  const float* x2   = (const float*)d_in[1];
  const float* Wq   = (const float*)d_in[2];
  const float* Wk   = (const float*)d_in[3];
  const float* Wv1  = (const float*)d_in[4];
  const float* Wv2  = (const float*)d_in[5];
  const float* Wrel = (const float*)d_in[6];
  const float* rpb  = (const float*)d_in[7];
  const float* Wo1  = (const float*)d_in[8];
  const float* bo1  = (const float*)d_in[9];
  const float* Wo2  = (const float*)d_in[10];
  const float* bo2  = (const float*)d_in[11];
  float* out = (float*)d_out;

  char* base = (char*)d_ws;
  size_t off = 0;
  auto alloc = [&](size_t bytes) -> void* {
    void* p = base + off; off += (bytes + 255) & ~(size_t)255; return p;
  };
  float* pos   = (float*)alloc((size_t)NPOS * 192 * 4);
  f16*   relq  = (f16*)  alloc((size_t)NH * NPOS * 64 * 2);
  f16*   qh    = (f16*)  alloc((size_t)16 * NSEQ * 64 * 2);
  f16*   kbh   = (f16*)  alloc((size_t)16 * NSEQ * 64 * 2);
  f16*   v1h   = (f16*)  alloc((size_t)16 * NSEQ * 64 * 2);
  f16*   v2h   = (f16*)  alloc((size_t)16 * NSEQ * 64 * 2);
  f16*   o1acc = (f16*)  alloc((size_t)2 * NSEQ * 512 * 2);
  f16*   o2acc = (f16*)  alloc((size_t)2 * NSEQ * 512 * 2);
  size_t baseB = off;

  int chunk = 1;
  for (int c = 16; c >= 1; c >>= 1) {
    size_t needB = baseB + (size_t)c * (NSEQ * (size_t)NSEQ * 2 + NSEQ * 32 * 4);
    if (needB <= ws_size) { chunk = c; break; }
  }
  f16*   attn = (f16*)(base + baseB);
  float* fac  = (float*)(base + baseB + (size_t)chunk * NSEQ * NSEQ * 2);

  pos_embed_k<<<(NPOS + 7) / 8, 256, 0, stream>>>(pos);
  relq_k<<<dim3(8, 64), 256, 0, stream>>>(pos, Wrel, relq);
  projx_k<1024, false><<<dim3(16, 64), 256, 0, stream>>>(x1, Wq, Wv1, qh, v1h, nullptr);
  projx_k<512,  true ><<<dim3(16, 64), 256, 0, stream>>>(x2, Wk, Wv2, kbh, v2h, rpb);

  for (int bh0 = 0; bh0 < 16; bh0 += chunk) {
    attn_k<<<dim3(32, chunk), 256, 0, stream>>>(qh, kbh, relq, attn, fac, bh0);
    pv_k<0><<<dim3(32, chunk), 256, 0, stream>>>(attn, v2h, fac, o1acc, bh0);
    pv_k<1><<<dim3(32, chunk), 256, 0, stream>>>(attn, v1h, fac, o2acc, bh0);
  }

  outproj_k<<<dim3(16, 128), 256, 0, stream>>>(o1acc, o2acc, Wo1, Wo2, bo1, bo2, out);
}

// Round 6
// 392.161 us; speedup vs baseline: 3.9874x; 1.1131x over previous
//
#include <hip/hip_runtime.h>
#include <math.h>

#define NSEQ 2048
#define NPOS 4095   // 2*NSEQ-1
#define NH   8

typedef _Float16 f16;
typedef f16 f16x8 __attribute__((ext_vector_type(8)));
typedef f16 f16x4 __attribute__((ext_vector_type(4)));
typedef float f32x4 __attribute__((ext_vector_type(4)));

#define MFMA16(a,b,c) __builtin_amdgcn_mfma_f32_16x16x32_f16(a,b,c,0,0,0)

__device__ __forceinline__ f16x8 cvt8(float4 a, float4 b) {
  f16x8 r = {(f16)a.x, (f16)a.y, (f16)a.z, (f16)a.w,
             (f16)b.x, (f16)b.y, (f16)b.z, (f16)b.w};
  return r;
}

// ---------------- positional embedding pos[NPOS][192], one lane per (t,f) ----
__global__ __launch_bounds__(256) void pos_embed_k(float* __restrict__ pos) {
  int t = blockIdx.x * 8 + (threadIdx.x >> 5);
  int f = threadIdx.x & 31;
  if (t >= NPOS) return;
  float dist = (float)(t - (NSEQ - 1));
  float ad = fabsf(dist);
  float sgn = (dist > 0.f) ? 1.f : ((dist < 0.f) ? -1.f : 0.f);
  double mean = 64.0 * (double)(f + 1);       // linspace(64,2048,32)
  double conc = (mean / 32.0) * (mean / 32.0);
  double rate = mean / 1024.0;
  double p = 0.0;
  if (ad > 0.f) {
    double lu = (conc - 1.0) * log((double)ad) - rate * (double)ad;
    double ln = lgamma(conc) - conc * log(rate);
    p = exp(lu - ln);
  }
  float pf = (float)p + 1e-8f;
  float gmax = pf;
  #pragma unroll
  for (int mk = 1; mk <= 16; mk <<= 1) gmax = fmaxf(gmax, __shfl_xor(gmax, mk));
  float fg = pf / gmax;
  float hl = exp2f(3.f + 8.f * (float)f * (1.f / 31.f));
  float fe = exp2f(-ad / hl);
  float cw = exp2f((float)(f + 1)) - 1.f;
  float fc = (cw > ad) ? 1.f : 0.f;
  float* row = pos + (size_t)t * 192;
  row[f]       = fe;       row[32 + f]  = fc;       row[64 + f]  = fg;
  row[96 + f]  = sgn * fe; row[128 + f] = sgn * fc; row[160 + f] = sgn * fg;
}

// ---------------- relq = pos @ Wrel -> f16 [h][NPOS][64] ----------------
__global__ __launch_bounds__(256) void relq_k(
    const float* __restrict__ A, const float* __restrict__ W, f16* __restrict__ relq)
{
  __shared__ f16 As[64][56];
  __shared__ f16 Bs[64][56];
  int tid = threadIdx.x, w = tid >> 6, lane = tid & 63, lr = lane >> 4, lc = lane & 15;
  int m0 = blockIdx.y * 64, n0 = blockIdx.x * 64;
  int ar = tid >> 2, ac = (tid & 3) * 8;
  int bk = tid >> 3, bn = (tid & 7) * 8;
  f32x4 acc[4] = {};
  for (int k0 = 0; k0 < 192; k0 += 32) {
    float4 a0 = make_float4(0.f,0.f,0.f,0.f), a1 = a0;
    if (m0 + ar < NPOS) {
      const float* ap = &A[(size_t)(m0 + ar) * 192 + k0 + ac];
      a0 = *(const float4*)ap; a1 = *(const float4*)(ap + 4);
    }
    *(f16x8*)&As[ar][ac] = cvt8(a0, a1);
    const float* bp = &W[(size_t)(k0 + bk) * 512 + n0 + bn];
    float4 b0 = *(const float4*)bp, b1 = *(const float4*)(bp + 4);
    f16 bv[8] = {(f16)b0.x,(f16)b0.y,(f16)b0.z,(f16)b0.w,(f16)b1.x,(f16)b1.y,(f16)b1.z,(f16)b1.w};
    #pragma unroll
    for (int tt = 0; tt < 8; tt++) { int t = (tt + bk) & 7; Bs[bn + t][bk] = bv[t]; }
    __syncthreads();
    f16x8 af = *(const f16x8*)&As[16*w + lc][8*lr];
    #pragma unroll
    for (int nt = 0; nt < 4; nt++) {
      f16x8 bf = *(const f16x8*)&Bs[16*nt + lc][8*lr];
      acc[nt] = MFMA16(af, bf, acc[nt]);
    }
    __syncthreads();
  }
  #pragma unroll
  for (int nt = 0; nt < 4; nt++)
    #pragma unroll
    for (int r = 0; r < 4; r++) {
      int m = m0 + 16*w + 4*lr + r;
      if (m >= NPOS) continue;
      int nn = n0 + 16*nt + lc;
      relq[((size_t)(nn >> 6) * NPOS + m) * 64 + (nn & 63)] = (f16)acc[nt][r];
    }
}

// ---------------- fused input projections: A[4096,KD] x (W1|W2)[KD,512] ----
template<int KD, bool SC1>
__global__ __launch_bounds__(256) void projx_k(
    const float* __restrict__ A, const float* __restrict__ W1, const float* __restrict__ W2,
    f16* __restrict__ O1, f16* __restrict__ O2, const float* __restrict__ rpb)
{
  __shared__ f16 As[64][56];
  __shared__ f16 Bs[64][56];
  int tid = threadIdx.x, w = tid >> 6, lane = tid & 63, lr = lane >> 4, lc = lane & 15;
  int m0 = blockIdx.y * 64, n0g = blockIdx.x * 64;
  bool first = (n0g < 512);
  const float* W = first ? W1 : W2;
  f16* O = first ? O1 : O2;
  int n0 = n0g & 511;
  int ar = tid >> 2, ac = (tid & 3) * 8;
  int bk = tid >> 3, bn = (tid & 7) * 8;
  f32x4 acc[4] = {};
  for (int k0 = 0; k0 < KD; k0 += 32) {
    const float* ap = &A[(size_t)(m0 + ar) * KD + k0 + ac];
    *(f16x8*)&As[ar][ac] = cvt8(*(const float4*)ap, *(const float4*)(ap + 4));
    const float* bp = &W[(size_t)(k0 + bk) * 512 + n0 + bn];
    float4 b0 = *(const float4*)bp, b1 = *(const float4*)(bp + 4);
    f16 bv[8] = {(f16)b0.x,(f16)b0.y,(f16)b0.z,(f16)b0.w,(f16)b1.x,(f16)b1.y,(f16)b1.z,(f16)b1.w};
    #pragma unroll
    for (int tt = 0; tt < 8; tt++) { int t = (tt + bk) & 7; Bs[bn + t][bk] = bv[t]; }
    __syncthreads();
    f16x8 af = *(const f16x8*)&As[16*w + lc][8*lr];
    #pragma unroll
    for (int nt = 0; nt < 4; nt++) {
      f16x8 bf = *(const f16x8*)&Bs[16*nt + lc][8*lr];
      acc[nt] = MFMA16(af, bf, acc[nt]);
    }
    __syncthreads();
  }
  #pragma unroll
  for (int nt = 0; nt < 4; nt++)
    #pragma unroll
    for (int r = 0; r < 4; r++) {
      int m = m0 + 16*w + 4*lr + r;
      int nn = n0 + 16*nt + lc;
      float vv = acc[nt][r];
      if (SC1 && first) vv = vv * 0.125f + rpb[nn];
      O[(((size_t)((m >> 11) * NH + (nn >> 6))) * NSEQ + (m & (NSEQ - 1))) * 64 + (nn & 63)] = (f16)vv;
    }
}

// ---------------- fused output projections ----------------
__global__ __launch_bounds__(256) void outproj_k(
    const f16* __restrict__ o1, const f16* __restrict__ o2,
    const float* __restrict__ Wo1, const float* __restrict__ Wo2,
    const float* __restrict__ bo1, const float* __restrict__ bo2,
    float* __restrict__ out)
{
  __shared__ f16 As[64][56];
  __shared__ f16 Bs[64][56];
  int by = blockIdx.y;
  bool first = (by < 64);
  const f16* A = first ? o1 : o2;
  const float* W = first ? Wo1 : Wo2;
  const float* bias = first ? bo1 : bo2;
  float* O = out + (first ? 0 : (size_t)4096 * 1024);
  int tid = threadIdx.x, w = tid >> 6, lane = tid & 63, lr = lane >> 4, lc = lane & 15;
  int m0 = (by & 63) * 64, n0 = blockIdx.x * 64;
  int ar = tid >> 2, ac = (tid & 3) * 8;
  int bk = tid >> 3, bn = (tid & 7) * 8;
  f32x4 acc[4] = {};
  for (int k0 = 0; k0 < 512; k0 += 32) {
    *(f16x8*)&As[ar][ac] = *(const f16x8*)&A[(size_t)(m0 + ar) * 512 + k0 + ac];
    const float* bp = &W[(size_t)(k0 + bk) * 1024 + n0 + bn];
    float4 b0 = *(const float4*)bp, b1 = *(const float4*)(bp + 4);
    f16 bv[8] = {(f16)b0.x,(f16)b0.y,(f16)b0.z,(f16)b0.w,(f16)b1.x,(f16)b1.y,(f16)b1.z,(f16)b1.w};
    #pragma unroll
    for (int tt = 0; tt < 8; tt++) { int t = (tt + bk) & 7; Bs[bn + t][bk] = bv[t]; }
    __syncthreads();
    f16x8 af = *(const f16x8*)&As[16*w + lc][8*lr];
    #pragma unroll
    for (int nt = 0; nt < 4; nt++) {
      f16x8 bf = *(const f16x8*)&Bs[16*nt + lc][8*lr];
      acc[nt] = MFMA16(af, bf, acc[nt]);
    }
    __syncthreads();
  }
  #pragma unroll
  for (int nt = 0; nt < 4; nt++)
    #pragma unroll
    for (int r = 0; r < 4; r++) {
      int m = m0 + 16*w + 4*lr + r;
      int n = n0 + 16*nt + lc;
      O[(size_t)m * 1024 + n] = acc[nt][r] + bias[n];
    }
}

// ---------------- fused logits + online softmax + out1 PV ----------------
// l[i,j] = q[i]·kb[j] + G[j, i-j+63];  G[j,n] = kb[j]·relq[nbase+n]
// writes P = exp(l - m_run_jt) (f16), fac[i][jt] = exp(m_jt - m_fin)/s (for pv2),
// and accumulates out1[i,d] = (1/s)·sum_j P·v2[j,d] in-register (flash).
// LDS (54400 B): Qs[64][72]@0 (prologue; G2[64][68] overlay), KBs[64][72]@9216
// (Pw per-wave [16][72] overlay), Rs[128][72]@18432, Vs[64][72]@36864,
// m_lds[32][65] f32 @46080.
__global__ __launch_bounds__(256) void attn_k(
    const f16* __restrict__ q, const f16* __restrict__ kb,
    const f16* __restrict__ relq, const f16* __restrict__ v2,
    f16* __restrict__ attn, float* __restrict__ fac,
    f16* __restrict__ o1acc, int bh0)
{
  __shared__ char smem[54400];
  f16 (*Qs)[72]  = (f16(*)[72])smem;
  f16 (*KBs)[72] = (f16(*)[72])(smem + 9216);
  f16 (*Rs)[72]  = (f16(*)[72])(smem + 18432);
  f16 (*Vs)[72]  = (f16(*)[72])(smem + 36864);
  f16 (*G2)[68]  = (f16(*)[68])smem;                  // overlay Qs
  float (*m_lds)[65] = (float(*)[65])(smem + 46080);
  int z = blockIdx.y, bh = bh0 + z, b = bh >> 3, h = bh & 7;
  int i0 = blockIdx.x * 64;
  int tid = threadIdx.x, w = tid >> 6, lane = tid & 63;
  int lr = lane >> 4, lc = lane & 15;
  f16 (*Pw)[72] = (f16(*)[72])(smem + 9216 + w * 2304);  // per-wave [16][72]

  {
    int row = tid >> 2, c0 = (tid & 3) * 16;
    const f16* qp = q + ((size_t)bh * NSEQ + i0 + row) * 64 + c0;
    *(f16x8*)&Qs[row][c0]     = *(const f16x8*)qp;
    *(f16x8*)&Qs[row][c0 + 8] = *(const f16x8*)(qp + 8);
  }
  __syncthreads();
  f16x8 qa0 = *(const f16x8*)&Qs[16*w + lc][8*lr];
  f16x8 qa1 = *(const f16x8*)&Qs[16*w + lc][32 + 8*lr];

  float m_run[4], ssum[4];
  f32x4 o1a[4] = {};   // out1 acc: [nt] x rows(4lr+r), cols 16nt+lc
  #pragma unroll
  for (int r = 0; r < 4; r++) { m_run[r] = -1e30f; ssum[r] = 0.f; }

  for (int jt = 0; jt < 32; jt++) {
    int j0 = jt * 64;
    {
      int row = tid >> 2, c0 = (tid & 3) * 16;
      const f16* kp = kb + ((size_t)bh * NSEQ + j0 + row) * 64 + c0;
      *(f16x8*)&KBs[row][c0]     = *(const f16x8*)kp;
      *(f16x8*)&KBs[row][c0 + 8] = *(const f16x8*)(kp + 8);
      // v2 tile transposed -> Vs[d][j]
      const f16* vp = v2 + ((size_t)bh * NSEQ + j0 + row) * 64 + c0;
      f16x8 u0 = *(const f16x8*)vp, u1 = *(const f16x8*)(vp + 8);
      #pragma unroll
      for (int tt = 0; tt < 8; tt++) {
        int t = (tt + row) & 7;
        Vs[c0 + t][row] = u0[t];
        Vs[c0 + 8 + t][row] = u1[t];
      }
      int rr = tid >> 1, rd = (tid & 1) * 32;
      int nbase = (NSEQ - 1) + i0 - j0 - 63;
      const f16* rp = relq + ((size_t)h * NPOS + nbase + rr) * 64 + rd;
      #pragma unroll
      for (int u = 0; u < 4; u++)
        *(f16x8*)&Rs[rr][rd + u*8] = *(const f16x8*)(rp + u*8);
    }
    __syncthreads();   // s1: staging visible
    f32x4 cacc[4];
    f16x8 ka0 = {}, ka1 = {};
    #pragma unroll
    for (int y = 0; y < 4; y++) {
      f16x8 b0 = *(const f16x8*)&KBs[16*y + lc][8*lr];
      f16x8 b1 = *(const f16x8*)&KBs[16*y + lc][32 + 8*lr];
      f32x4 t = {};
      t = MFMA16(qa0, b0, t);
      t = MFMA16(qa1, b1, t);
      cacc[y] = t;
      if (y == w) { ka0 = b0; ka1 = b1; }
    }
    #pragma unroll
    for (int g = 0; g < 8; g++) {
      f32x4 ga = {};
      ga = MFMA16(ka0, *(const f16x8*)&Rs[16*g + lc][8*lr], ga);
      ga = MFMA16(ka1, *(const f16x8*)&Rs[16*g + lc][32 + 8*lr], ga);
      int jj = 16*w + 4*lr;
      #pragma unroll
      for (int r = 0; r < 4; r++) {
        int ii = 16*g + lc + jj + r - 63;   // i = n + j - 63
        if ((unsigned)ii < 64u) G2[jj + r][ii] = (f16)ga[r];
      }
    }
    __syncthreads();   // s2: G2 complete; KBs frag reads done -> Pw overlay safe
    float l[4][4];
    #pragma unroll
    for (int y = 0; y < 4; y++) {
      f16x4 gv = *(const f16x4*)&G2[16*y + lc][16*w + 4*lr];
      #pragma unroll
      for (int r = 0; r < 4; r++) l[y][r] = cacc[y][r] + (float)gv[r];
    }
    #pragma unroll
    for (int r = 0; r < 4; r++) {
      float tm = fmaxf(fmaxf(l[0][r], l[1][r]), fmaxf(l[2][r], l[3][r]));
      #pragma unroll
      for (int mk = 1; mk <= 8; mk <<= 1) tm = fmaxf(tm, __shfl_xor(tm, mk));
      if (tm > m_run[r]) {
        float sc = __expf(m_run[r] - tm);
        ssum[r] *= sc;
        #pragma unroll
        for (int nt = 0; nt < 4; nt++) o1a[nt][r] *= sc;
        m_run[r] = tm;
      }
      float mnew = m_run[r];
      float ps = 0.f;
      #pragma unroll
      for (int y = 0; y < 4; y++) {
        float p = __expf(l[y][r] - mnew);
        ps += p;
        Pw[4*lr + r][16*y + lc] = (f16)p;
      }
      ssum[r] += ps;
      if (lc == 0) m_lds[jt][16*w + 4*lr + r] = mnew;
    }
    __syncthreads();   // s3: Pw writes visible
    {
      int prow = lane >> 2, pc0 = (lane & 3) * 16;
      f16* ap = attn + ((size_t)z * NSEQ + i0 + 16*w + prow) * NSEQ + j0 + pc0;
      *(f16x8*)ap       = *(const f16x8*)&Pw[prow][pc0];
      *(f16x8*)(ap + 8) = *(const f16x8*)&Pw[prow][pc0 + 8];
    }
    // out1 PV: o1a += P(own 16 rows) x v2-tile
    {
      f16x8 pa0 = *(const f16x8*)&Pw[lc][8*lr];
      f16x8 pa1 = *(const f16x8*)&Pw[lc][32 + 8*lr];
      #pragma unroll
      for (int nt = 0; nt < 4; nt++) {
        f16x8 vf0 = *(const f16x8*)&Vs[16*nt + lc][8*lr];
        f16x8 vf1 = *(const f16x8*)&Vs[16*nt + lc][32 + 8*lr];
        o1a[nt] = MFMA16(pa0, vf0, o1a[nt]);
        o1a[nt] = MFMA16(pa1, vf1, o1a[nt]);
      }
    }
    __syncthreads();   // s4: Pw/G2/Vs reads done -> next tile may restage
  }
  // epilogue: reduce s per row; write fac (for pv2) and out1
  float invs[4];
  #pragma unroll
  for (int r = 0; r < 4; r++) {
    float s = ssum[r];
    #pragma unroll
    for (int mk = 1; mk <= 8; mk <<= 1) s += __shfl_xor(s, mk);
    invs[r] = 1.f / s;
    int il = 16*w + 4*lr + r;
    float mf = m_run[r];
    #pragma unroll
    for (int jtb = 0; jtb < 2; jtb++) {
      int jt = jtb * 16 + lc;
      float fv = __expf(m_lds[jt][il] - mf) * invs[r];
      fac[((size_t)z * NSEQ + i0 + il) * 32 + jt] = fv;
    }
  }
  #pragma unroll
  for (int nt = 0; nt < 4; nt++)
    #pragma unroll
    for (int r = 0; r < 4; r++) {
      int row = i0 + 16*w + 4*lr + r;
      o1acc[((size_t)b * NSEQ + row) * 512 + h * 64 + 16*nt + lc] = (f16)(o1a[nt][r] * invs[r]);
    }
}

// ---------------- pv2: out2[j,d] = sum_i (fac[i][jt] P[i,j]) v1[i,d] ----------------
__global__ __launch_bounds__(256) void pv2_k(const f16* __restrict__ attn,
    const f16* __restrict__ v, const float* __restrict__ fac,
    f16* __restrict__ oacc, int bh0)
{
  __shared__ f16 As[64][56];
  __shared__ f16 Vs[64][56];
  int z = blockIdx.y, bh = bh0 + z, b = bh >> 3, h = bh & 7;
  int r0 = blockIdx.x * 64;
  int tid = threadIdx.x, w = tid >> 6, lane = tid & 63;
  int lr = lane >> 4, lc = lane & 15;
  f32x4 acc[4] = {};
  for (int k0 = 0; k0 < NSEQ; k0 += 32) {
    {
      int kk = tid >> 3, c0 = (tid & 7) * 8;
      f16x8 av = *(const f16x8*)&attn[((size_t)z * NSEQ + k0 + kk) * NSEQ + r0 + c0];
      f16 sc = (f16)fac[((size_t)z * NSEQ + k0 + kk) * 32 + (r0 >> 6)];
      #pragma unroll
      for (int tt = 0; tt < 8; tt++) { int t = (tt + kk) & 7; As[c0 + t][kk] = av[t] * sc; }
    }
    int kk = tid >> 3, d0 = (tid & 7) * 8;
    f16x8 vv = *(const f16x8*)&v[((size_t)bh * NSEQ + k0 + kk) * 64 + d0];
    #pragma unroll
    for (int tt = 0; tt < 8; tt++) { int t = (tt + kk) & 7; Vs[d0 + t][kk] = vv[t]; }
    __syncthreads();
    f16x8 af = *(const f16x8*)&As[16*w + lc][8*lr];
    #pragma unroll
    for (int nt = 0; nt < 4; nt++) {
      f16x8 vf = *(const f16x8*)&Vs[16*nt + lc][8*lr];
      acc[nt] = MFMA16(af, vf, acc[nt]);
    }
    __syncthreads();
  }
  #pragma unroll
  for (int nt = 0; nt < 4; nt++)
    #pragma unroll
    for (int r = 0; r < 4; r++) {
      int row = r0 + 16*w + 4*lr + r;
      oacc[((size_t)b * NSEQ + row) * 512 + h * 64 + 16*nt + lc] = (f16)acc[nt][r];
    }
}

extern "C" void kernel_launch(void* const* d_in, const int* in_sizes, int n_in,
                              void* d_out, int out_size, void* d_ws, size_t ws_size,
                              hipStream_t stream) {
  const float* x1   = (const float*)d_in[0];
  const float* x2   = (const float*)d_in[1];
  const float* Wq   = (const float*)d_in[2];
  const float* Wk   = (const float*)d_in[3];
  const float* Wv1  = (const float*)d_in[4];
  const float* Wv2  = (const float*)d_in[5];
  const float* Wrel = (const float*)d_in[6];
  const float* rpb  = (const float*)d_in[7];
  const float* Wo1  = (const float*)d_in[8];
  const float* bo1  = (const float*)d_in[9];
  const float* Wo2  = (const float*)d_in[10];
  const float* bo2  = (const float*)d_in[11];
  float* out = (float*)d_out;

  char* base = (char*)d_ws;
  size_t off = 0;
  auto alloc = [&](size_t bytes) -> void* {
    void* p = base + off; off += (bytes + 255) & ~(size_t)255; return p;
  };
  float* pos   = (float*)alloc((size_t)NPOS * 192 * 4);
  f16*   relq  = (f16*)  alloc((size_t)NH * NPOS * 64 * 2);
  f16*   qh    = (f16*)  alloc((size_t)16 * NSEQ * 64 * 2);
  f16*   kbh   = (f16*)  alloc((size_t)16 * NSEQ * 64 * 2);
  f16*   v1h   = (f16*)  alloc((size_t)16 * NSEQ * 64 * 2);
  f16*   v2h   = (f16*)  alloc((size_t)16 * NSEQ * 64 * 2);
  f16*   o1acc = (f16*)  alloc((size_t)2 * NSEQ * 512 * 2);
  f16*   o2acc = (f16*)  alloc((size_t)2 * NSEQ * 512 * 2);
  size_t baseB = off;

  int chunk = 1;
  for (int c = 16; c >= 1; c >>= 1) {
    size_t needB = baseB + (size_t)c * (NSEQ * (size_t)NSEQ * 2 + NSEQ * 32 * 4);
    if (needB <= ws_size) { chunk = c; break; }
  }
  f16*   attn = (f16*)(base + baseB);
  float* fac  = (float*)(base + baseB + (size_t)chunk * NSEQ * NSEQ * 2);

  pos_embed_k<<<(NPOS + 7) / 8, 256, 0, stream>>>(pos);
  relq_k<<<dim3(8, 64), 256, 0, stream>>>(pos, Wrel, relq);
  projx_k<1024, false><<<dim3(16, 64), 256, 0, stream>>>(x1, Wq, Wv1, qh, v1h, nullptr);
  projx_k<512,  true ><<<dim3(16, 64), 256, 0, stream>>>(x2, Wk, Wv2, kbh, v2h, rpb);

  for (int bh0 = 0; bh0 < 16; bh0 += chunk) {
    attn_k<<<dim3(32, chunk), 256, 0, stream>>>(qh, kbh, relq, v2h, attn, fac, o1acc, bh0);
    pv2_k<<<dim3(32, chunk), 256, 0, stream>>>(attn, v1h, fac, o2acc, bh0);
  }

  outproj_k<<<dim3(16, 128), 256, 0, stream>>>(o1acc, o2acc, Wo1, Wo2, bo1, bo2, out);
}